// Round 3
// baseline (98.186 us; speedup 1.0000x reference)
//
#include <hip/hip_runtime.h>

// LVAE_shGLM encoder, fused bf16-MFMA implementation for gfx950.
// Round 3: LDS cut to 73.4 KB -> 2 blocks/CU (2 waves/SIMD) so barrier/stage
// stalls of one block overlap the other's compute. Weight pipe = 2 x 4KB
// quarter-tiles (60 phases, 1 global_load_lds_dwordx4 per wave per phase);
// GEMM2/GEMM4 B-frags + biases read directly from global (L2-hot).
//
//   h_mid  = relu(windows @ W1 + b1)   windows[t,k] = pad[t+k]
//   mu_mid = h_mid @ W2 + b2           -> out[:, 0:4]
//   h_leaf = relu(h_mid @ Wl1 + bl1)
//   mu_leaf= h_leaf @ Wl2 + bl2        -> out[:, 4:20]

typedef __bf16 bf16;
typedef __bf16 bf16x8 __attribute__((ext_vector_type(8)));
typedef float  f32x4  __attribute__((ext_vector_type(4)));

constexpr int T_DATA = 100000;
constexpr int T_V    = 100;
constexpr int WIN    = 199;   // 2*T_V - 1
constexpr int HID    = 256;
constexpr int BT     = 128;   // timesteps per block
constexpr int RPW    = 32;    // rows per wave (2 MFMA row-tiles)
constexpr int NKT    = 15;    // 7 (W1, K padded 199->224) + 8 (Wl1)

// ws layout in bf16 elements (written by pack_weights):
//   [0      .. 57343 ] PW1   7 kt-tiles x 16 ct x 512
//   [57344  ..122879 ] PWl1  8 kt-tiles x 16 ct x 512   (contiguous with PW1)
//   [122880 ..126975 ] PW2   8 kt x 512
//   [126976 ..131071 ] PWl2  8 kt x 512
constexpr int PW1_OFF  = 0;
constexpr int PWL1_OFF = 112 * 512;
constexpr int PW2_OFF  = PWL1_OFF + 128 * 512;   // 122880
constexpr int PWL2_OFF = PW2_OFF + 8 * 512;      // 126976

__global__ void pack_weights(const float* __restrict__ W1, const float* __restrict__ W2,
                             const float* __restrict__ Wl1, const float* __restrict__ Wl2,
                             bf16* __restrict__ ws) {
  const int gid  = blockIdx.x * blockDim.x + threadIdx.x;  // [0, 16384)
  const int lane = gid & 63;
  const int grp  = gid >> 6;        // [0, 256)
  const int m    = lane & 15;       // fragment col (N)
  const int g    = lane >> 4;       // k-group
  bf16x8 v;
  if (grp < 112) {                  // PW1: grp = kt*16 + nt
    const int kt = grp >> 4, nt = grp & 15, n = nt * 16 + m;
#pragma unroll
    for (int j = 0; j < 8; ++j) {
      const int k = kt * 32 + g * 8 + j;
      v[j] = (k < WIN) ? (bf16)W1[k * HID + n] : (bf16)0.0f;
    }
  } else if (grp < 240) {           // PWl1
    const int q = grp - 112;
    const int kt = q >> 4, nt = q & 15, n = nt * 16 + m;
#pragma unroll
    for (int j = 0; j < 8; ++j) {
      const int k = kt * 32 + g * 8 + j;
      v[j] = (bf16)Wl1[k * HID + n];
    }
  } else if (grp < 248) {           // PW2: only cols 0..3 real, rest zero
    const int kt = grp - 240;
#pragma unroll
    for (int j = 0; j < 8; ++j) {
      const int k = kt * 32 + g * 8 + j;
      v[j] = (m < 4) ? (bf16)W2[k * 4 + m] : (bf16)0.0f;
    }
  } else {                          // PWl2: 16 cols
    const int kt = grp - 248;
#pragma unroll
    for (int j = 0; j < 8; ++j) {
      const int k = kt * 32 + g * 8 + j;
      v[j] = (bf16)Wl2[k * 16 + m];
    }
  }
  *reinterpret_cast<bf16x8*>(ws + (size_t)gid * 8) = v;
}

__global__ __launch_bounds__(256, 2) void fused_enc(
    const float* __restrict__ V, const float* __restrict__ b1,
    const float* __restrict__ b2, const float* __restrict__ bl1,
    const float* __restrict__ bl2, const bf16* __restrict__ ws,
    float* __restrict__ out) {
  __shared__ float Vs[BT + 224];        // 1408 B fp32 window slice
  __shared__ bf16  hbuf[BT * HID];      // 64 KB, XOR-swizzled, wave-private rows
  __shared__ bf16  bwe[2][2048];        // 8 KB: double-buffered 4-ct quarter tile
  // total 75136 B -> 2 blocks/CU

  const int tid  = threadIdx.x;
  const int lane = tid & 63;
  const int w    = tid >> 6;
  const int m    = lane & 15;           // A-frag row / C col
  const int g    = lane >> 4;           // k-group / C row-group
  const long t0  = (long)blockIdx.x * BT;

  // ---- prologue: stage quarter 0, fill Vs ----
  __builtin_amdgcn_global_load_lds(
      (const __attribute__((address_space(1))) void*)(ws + w * 512 + lane * 8),
      (__attribute__((address_space(3))) void*)(&bwe[0][w * 512]), 16, 0, 0);
  for (int i = tid; i < BT + 224; i += 256) {
    const long src = t0 - (T_V - 1) + i;
    Vs[i] = (src >= 0 && src < T_DATA) ? V[src] : 0.0f;
  }
  __syncthreads();   // drains vmcnt: bwe[0] + Vs resident

  const int r0   = w * RPW;
  const int ar0  = r0 + m;
  const int ar1  = r0 + 16 + m;
  const int swz0 = (ar0 & 7) << 3;
  const int swz1 = (ar1 & 7) << 3;

  f32x4 acc[2][16];
#pragma unroll
  for (int rt = 0; rt < 2; ++rt)
#pragma unroll
    for (int ct = 0; ct < 16; ++ct) acc[rt][ct] = (f32x4){0.f, 0.f, 0.f, 0.f};
  f32x4 mu2[2] = {(f32x4){0.f, 0.f, 0.f, 0.f}, (f32x4){0.f, 0.f, 0.f, 0.f}};

  // ---- main pipeline: 15 kt x 4 quarter-phases ----
  // kt 0..6 = GEMM1 (A from Vs), kt 7..14 = GEMM3 (+fused GEMM2, A from hbuf)
#pragma unroll
  for (int kt = 0; kt < NKT; ++kt) {
    bf16x8 a0, a1, bw2;
    // A-frags built once per kt (constant across the 4 quarters)
    if (kt < 7) {
      const int kb = kt * 32 + g * 8;
#pragma unroll
      for (int j = 0; j < 8; ++j) {
        a0[j] = (bf16)Vs[ar0 + kb + j];
        a1[j] = (bf16)Vs[ar1 + kb + j];
      }
    } else {
      const int kb = (kt - 7) * 32 + g * 8;
      a0 = *reinterpret_cast<const bf16x8*>(&hbuf[ar0 * HID + (kb ^ swz0)]);
      a1 = *reinterpret_cast<const bf16x8*>(&hbuf[ar1 * HID + (kb ^ swz1)]);
      // W2 frag for fused GEMM2, from global (L2-hot), used at q==3
      bw2 = *reinterpret_cast<const bf16x8*>(ws + PW2_OFF + (size_t)(kt - 7) * 512 + lane * 8);
    }

#pragma unroll
    for (int q = 0; q < 4; ++q) {
      const int phase = kt * 4 + q;
      const int cur   = phase & 1;
      if (phase + 1 < NKT * 4) {       // prefetch next quarter into other buffer
        __builtin_amdgcn_global_load_lds(
            (const __attribute__((address_space(1))) void*)
                (ws + (size_t)(phase + 1) * 2048 + w * 512 + lane * 8),
            (__attribute__((address_space(3))) void*)(&bwe[cur ^ 1][w * 512]), 16, 0, 0);
      }
      const bf16* bp = bwe[cur] + lane * 8;
#pragma unroll
      for (int c4 = 0; c4 < 4; ++c4) {
        const bf16x8 b = *reinterpret_cast<const bf16x8*>(bp + c4 * 512);
        const int ct = q * 4 + c4;
        acc[0][ct] = __builtin_amdgcn_mfma_f32_16x16x32_bf16(a0, b, acc[0][ct], 0, 0, 0);
        acc[1][ct] = __builtin_amdgcn_mfma_f32_16x16x32_bf16(a1, b, acc[1][ct], 0, 0, 0);
      }

      if (q == 3) {
        if (kt >= 7) {                 // fused GEMM2: mu_mid += h_mid_k @ W2_k
          mu2[0] = __builtin_amdgcn_mfma_f32_16x16x32_bf16(a0, bw2, mu2[0], 0, 0, 0);
          mu2[1] = __builtin_amdgcn_mfma_f32_16x16x32_bf16(a1, bw2, mu2[1], 0, 0, 0);
        }
        if (kt == 6) {
          // h_mid epilogue: bias+relu, store to own hbuf rows (swizzled), reset acc
#pragma unroll
          for (int ct = 0; ct < 16; ++ct) {
            const float bb = b1[ct * 16 + m];
#pragma unroll
            for (int rt = 0; rt < 2; ++rt) {
#pragma unroll
              for (int j = 0; j < 4; ++j) {
                const int r = r0 + rt * 16 + g * 4 + j;
                float h = fmaxf(acc[rt][ct][j] + bb, 0.0f);
                const int c = ct * 16 + m;
                hbuf[r * HID + (c ^ ((r & 7) << 3))] = (bf16)h;
                acc[rt][ct][j] = 0.0f;
              }
            }
          }
        }
      }
      __syncthreads();   // all waves done with bwe[cur]; next quarter landed
    }
  }

  // ---- preload Wl2 frags (global, L2-hot) so latency hides under h_leaf stores ----
  bf16x8 bwl2[8];
#pragma unroll
  for (int kq = 0; kq < 8; ++kq)
    bwl2[kq] = *reinterpret_cast<const bf16x8*>(ws + PWL2_OFF + (size_t)kq * 512 + lane * 8);

  // ---- h_leaf epilogue: bias+relu, overwrite own hbuf rows ----
#pragma unroll
  for (int ct = 0; ct < 16; ++ct) {
    const float bb = bl1[ct * 16 + m];
#pragma unroll
    for (int rt = 0; rt < 2; ++rt) {
#pragma unroll
      for (int j = 0; j < 4; ++j) {
        const int r = r0 + rt * 16 + g * 4 + j;
        float h = fmaxf(acc[rt][ct][j] + bb, 0.0f);
        const int c = ct * 16 + m;
        hbuf[r * HID + (c ^ ((r & 7) << 3))] = (bf16)h;
      }
    }
  }

  // ---- GEMM4: mu_leaf = h_leaf @ Wl2 (wave-private, no barriers) ----
  f32x4 mu4[2] = {(f32x4){0.f, 0.f, 0.f, 0.f}, (f32x4){0.f, 0.f, 0.f, 0.f}};
#pragma unroll
  for (int kq = 0; kq < 8; ++kq) {
    const int kb = kq * 32 + g * 8;
    const bf16x8 a0 = *reinterpret_cast<const bf16x8*>(&hbuf[ar0 * HID + (kb ^ swz0)]);
    const bf16x8 a1 = *reinterpret_cast<const bf16x8*>(&hbuf[ar1 * HID + (kb ^ swz1)]);
    mu4[0] = __builtin_amdgcn_mfma_f32_16x16x32_bf16(a0, bwl2[kq], mu4[0], 0, 0, 0);
    mu4[1] = __builtin_amdgcn_mfma_f32_16x16x32_bf16(a1, bwl2[kq], mu4[1], 0, 0, 0);
  }

  // ---- epilogue: out[t, 0:4] = mu_mid, out[t, 4:20] = mu_leaf ----
  const float bl2v = bl2[m];
  const float b2v  = (m < 4) ? b2[m] : 0.0f;
#pragma unroll
  for (int rt = 0; rt < 2; ++rt) {
#pragma unroll
    for (int j = 0; j < 4; ++j) {
      const long t = t0 + r0 + rt * 16 + g * 4 + j;  // C layout: row=(lane>>4)*4+reg, col=lane&15
      if (t < T_DATA) {
        out[t * 20 + 4 + m] = mu4[rt][j] + bl2v;
        if (m < 4) out[t * 20 + m] = mu2[rt][j] + b2v;
      }
    }
  }
}

extern "C" void kernel_launch(void* const* d_in, const int* in_sizes, int n_in,
                              void* d_out, int out_size, void* d_ws, size_t ws_size,
                              hipStream_t stream) {
  const float* V   = (const float*)d_in[0];
  const float* W1  = (const float*)d_in[1];
  const float* b1  = (const float*)d_in[2];
  const float* W2  = (const float*)d_in[3];
  const float* b2  = (const float*)d_in[4];
  const float* Wl1 = (const float*)d_in[5];
  const float* bl1 = (const float*)d_in[6];
  const float* Wl2 = (const float*)d_in[7];
  const float* bl2 = (const float*)d_in[8];
  bf16* ws = (bf16*)d_ws;   // needs 262144 bytes
  float* out = (float*)d_out;

  pack_weights<<<64, 256, 0, stream>>>(W1, W2, Wl1, Wl2, ws);

  const int grid = (T_DATA + BT - 1) / BT;   // 782
  fused_enc<<<grid, 256, 0, stream>>>(V, b1, b2, bl1, bl2, ws, out);
}

// Round 4
// 94.237 us; speedup vs baseline: 1.0419x; 1.0419x over previous
//
#include <hip/hip_runtime.h>

// LVAE_shGLM encoder, fused bf16-MFMA implementation for gfx950.
// Round 4: round-3 structure (2 blocks/CU via 73.4 KB LDS, 60-phase quarter-tile
// weight pipe) but WITHOUT the 128-VGPR launch_bounds cap that caused
// accumulator spill (WRITE_SIZE 63 MB). Natural allocation ~200-230 VGPR still
// allows 2 waves/SIMD (pool = 512/SIMD).
//
//   h_mid  = relu(windows @ W1 + b1)   windows[t,k] = pad[t+k]
//   mu_mid = h_mid @ W2 + b2           -> out[:, 0:4]
//   h_leaf = relu(h_mid @ Wl1 + bl1)
//   mu_leaf= h_leaf @ Wl2 + bl2        -> out[:, 4:20]

typedef __bf16 bf16;
typedef __bf16 bf16x8 __attribute__((ext_vector_type(8)));
typedef float  f32x4  __attribute__((ext_vector_type(4)));

constexpr int T_DATA = 100000;
constexpr int T_V    = 100;
constexpr int WIN    = 199;   // 2*T_V - 1
constexpr int HID    = 256;
constexpr int BT     = 128;   // timesteps per block
constexpr int RPW    = 32;    // rows per wave (2 MFMA row-tiles)
constexpr int NKT    = 15;    // 7 (W1, K padded 199->224) + 8 (Wl1)

// ws layout in bf16 elements (written by pack_weights):
//   [0      .. 57343 ] PW1   7 kt-tiles x 16 ct x 512
//   [57344  ..122879 ] PWl1  8 kt-tiles x 16 ct x 512   (contiguous with PW1)
//   [122880 ..126975 ] PW2   8 kt x 512
//   [126976 ..131071 ] PWl2  8 kt x 512
constexpr int PW1_OFF  = 0;
constexpr int PWL1_OFF = 112 * 512;
constexpr int PW2_OFF  = PWL1_OFF + 128 * 512;   // 122880
constexpr int PWL2_OFF = PW2_OFF + 8 * 512;      // 126976

__global__ void pack_weights(const float* __restrict__ W1, const float* __restrict__ W2,
                             const float* __restrict__ Wl1, const float* __restrict__ Wl2,
                             bf16* __restrict__ ws) {
  const int gid  = blockIdx.x * blockDim.x + threadIdx.x;  // [0, 16384)
  const int lane = gid & 63;
  const int grp  = gid >> 6;        // [0, 256)
  const int m    = lane & 15;       // fragment col (N)
  const int g    = lane >> 4;       // k-group
  bf16x8 v;
  if (grp < 112) {                  // PW1: grp = kt*16 + nt
    const int kt = grp >> 4, nt = grp & 15, n = nt * 16 + m;
#pragma unroll
    for (int j = 0; j < 8; ++j) {
      const int k = kt * 32 + g * 8 + j;
      v[j] = (k < WIN) ? (bf16)W1[k * HID + n] : (bf16)0.0f;
    }
  } else if (grp < 240) {           // PWl1
    const int q = grp - 112;
    const int kt = q >> 4, nt = q & 15, n = nt * 16 + m;
#pragma unroll
    for (int j = 0; j < 8; ++j) {
      const int k = kt * 32 + g * 8 + j;
      v[j] = (bf16)Wl1[k * HID + n];
    }
  } else if (grp < 248) {           // PW2: only cols 0..3 real, rest zero
    const int kt = grp - 240;
#pragma unroll
    for (int j = 0; j < 8; ++j) {
      const int k = kt * 32 + g * 8 + j;
      v[j] = (m < 4) ? (bf16)W2[k * 4 + m] : (bf16)0.0f;
    }
  } else {                          // PWl2: 16 cols
    const int kt = grp - 248;
#pragma unroll
    for (int j = 0; j < 8; ++j) {
      const int k = kt * 32 + g * 8 + j;
      v[j] = (bf16)Wl2[k * 16 + m];
    }
  }
  *reinterpret_cast<bf16x8*>(ws + (size_t)gid * 8) = v;
}

__global__ __launch_bounds__(256, 1) void fused_enc(
    const float* __restrict__ V, const float* __restrict__ b1,
    const float* __restrict__ b2, const float* __restrict__ bl1,
    const float* __restrict__ bl2, const bf16* __restrict__ ws,
    float* __restrict__ out) {
  __shared__ float Vs[BT + 224];        // 1408 B fp32 window slice
  __shared__ bf16  hbuf[BT * HID];      // 64 KB, XOR-swizzled, wave-private rows
  __shared__ bf16  bwe[2][2048];        // 8 KB: double-buffered 4-ct quarter tile
  // total 75136 B -> 2 blocks/CU

  const int tid  = threadIdx.x;
  const int lane = tid & 63;
  const int w    = tid >> 6;
  const int m    = lane & 15;           // A-frag row / C col
  const int g    = lane >> 4;           // k-group / C row-group
  const long t0  = (long)blockIdx.x * BT;

  // ---- prologue: stage quarter 0, fill Vs ----
  __builtin_amdgcn_global_load_lds(
      (const __attribute__((address_space(1))) void*)(ws + w * 512 + lane * 8),
      (__attribute__((address_space(3))) void*)(&bwe[0][w * 512]), 16, 0, 0);
  for (int i = tid; i < BT + 224; i += 256) {
    const long src = t0 - (T_V - 1) + i;
    Vs[i] = (src >= 0 && src < T_DATA) ? V[src] : 0.0f;
  }
  __syncthreads();   // drains vmcnt: bwe[0] + Vs resident

  const int r0   = w * RPW;
  const int ar0  = r0 + m;
  const int ar1  = r0 + 16 + m;
  const int swz0 = (ar0 & 7) << 3;
  const int swz1 = (ar1 & 7) << 3;

  f32x4 acc[2][16];
#pragma unroll
  for (int rt = 0; rt < 2; ++rt)
#pragma unroll
    for (int ct = 0; ct < 16; ++ct) acc[rt][ct] = (f32x4){0.f, 0.f, 0.f, 0.f};
  f32x4 mu2[2] = {(f32x4){0.f, 0.f, 0.f, 0.f}, (f32x4){0.f, 0.f, 0.f, 0.f}};

  // ---- main pipeline: 15 kt x 4 quarter-phases ----
  // kt 0..6 = GEMM1 (A from Vs), kt 7..14 = GEMM3 (+fused GEMM2, A from hbuf)
#pragma unroll
  for (int kt = 0; kt < NKT; ++kt) {
    bf16x8 a0, a1, bw2;
    // A-frags built once per kt (constant across the 4 quarters)
    if (kt < 7) {
      const int kb = kt * 32 + g * 8;
#pragma unroll
      for (int j = 0; j < 8; ++j) {
        a0[j] = (bf16)Vs[ar0 + kb + j];
        a1[j] = (bf16)Vs[ar1 + kb + j];
      }
    } else {
      const int kb = (kt - 7) * 32 + g * 8;
      a0 = *reinterpret_cast<const bf16x8*>(&hbuf[ar0 * HID + (kb ^ swz0)]);
      a1 = *reinterpret_cast<const bf16x8*>(&hbuf[ar1 * HID + (kb ^ swz1)]);
      // W2 frag for fused GEMM2, from global (L2-hot), used at q==3
      bw2 = *reinterpret_cast<const bf16x8*>(ws + PW2_OFF + (size_t)(kt - 7) * 512 + lane * 8);
    }

#pragma unroll
    for (int q = 0; q < 4; ++q) {
      const int phase = kt * 4 + q;
      const int cur   = phase & 1;
      if (phase + 1 < NKT * 4) {       // prefetch next quarter into other buffer
        __builtin_amdgcn_global_load_lds(
            (const __attribute__((address_space(1))) void*)
                (ws + (size_t)(phase + 1) * 2048 + w * 512 + lane * 8),
            (__attribute__((address_space(3))) void*)(&bwe[cur ^ 1][w * 512]), 16, 0, 0);
      }
      const bf16* bp = bwe[cur] + lane * 8;
#pragma unroll
      for (int c4 = 0; c4 < 4; ++c4) {
        const bf16x8 b = *reinterpret_cast<const bf16x8*>(bp + c4 * 512);
        const int ct = q * 4 + c4;
        acc[0][ct] = __builtin_amdgcn_mfma_f32_16x16x32_bf16(a0, b, acc[0][ct], 0, 0, 0);
        acc[1][ct] = __builtin_amdgcn_mfma_f32_16x16x32_bf16(a1, b, acc[1][ct], 0, 0, 0);
      }

      if (q == 3) {
        if (kt >= 7) {                 // fused GEMM2: mu_mid += h_mid_k @ W2_k
          mu2[0] = __builtin_amdgcn_mfma_f32_16x16x32_bf16(a0, bw2, mu2[0], 0, 0, 0);
          mu2[1] = __builtin_amdgcn_mfma_f32_16x16x32_bf16(a1, bw2, mu2[1], 0, 0, 0);
        }
        if (kt == 6) {
          // h_mid epilogue: bias+relu, store to own hbuf rows (swizzled), reset acc
#pragma unroll
          for (int ct = 0; ct < 16; ++ct) {
            const float bb = b1[ct * 16 + m];
#pragma unroll
            for (int rt = 0; rt < 2; ++rt) {
#pragma unroll
              for (int j = 0; j < 4; ++j) {
                const int r = r0 + rt * 16 + g * 4 + j;
                float h = fmaxf(acc[rt][ct][j] + bb, 0.0f);
                const int c = ct * 16 + m;
                hbuf[r * HID + (c ^ ((r & 7) << 3))] = (bf16)h;
                acc[rt][ct][j] = 0.0f;
              }
            }
          }
        }
      }
      __syncthreads();   // all waves done with bwe[cur]; next quarter landed
    }
  }

  // ---- preload Wl2 frags (global, L2-hot) so latency hides under h_leaf stores ----
  bf16x8 bwl2[8];
#pragma unroll
  for (int kq = 0; kq < 8; ++kq)
    bwl2[kq] = *reinterpret_cast<const bf16x8*>(ws + PWL2_OFF + (size_t)kq * 512 + lane * 8);

  // ---- h_leaf epilogue: bias+relu, overwrite own hbuf rows ----
#pragma unroll
  for (int ct = 0; ct < 16; ++ct) {
    const float bb = bl1[ct * 16 + m];
#pragma unroll
    for (int rt = 0; rt < 2; ++rt) {
#pragma unroll
      for (int j = 0; j < 4; ++j) {
        const int r = r0 + rt * 16 + g * 4 + j;
        float h = fmaxf(acc[rt][ct][j] + bb, 0.0f);
        const int c = ct * 16 + m;
        hbuf[r * HID + (c ^ ((r & 7) << 3))] = (bf16)h;
      }
    }
  }

  // ---- GEMM4: mu_leaf = h_leaf @ Wl2 (wave-private, no barriers) ----
  f32x4 mu4[2] = {(f32x4){0.f, 0.f, 0.f, 0.f}, (f32x4){0.f, 0.f, 0.f, 0.f}};
#pragma unroll
  for (int kq = 0; kq < 8; ++kq) {
    const int kb = kq * 32 + g * 8;
    const bf16x8 a0 = *reinterpret_cast<const bf16x8*>(&hbuf[ar0 * HID + (kb ^ swz0)]);
    const bf16x8 a1 = *reinterpret_cast<const bf16x8*>(&hbuf[ar1 * HID + (kb ^ swz1)]);
    mu4[0] = __builtin_amdgcn_mfma_f32_16x16x32_bf16(a0, bwl2[kq], mu4[0], 0, 0, 0);
    mu4[1] = __builtin_amdgcn_mfma_f32_16x16x32_bf16(a1, bwl2[kq], mu4[1], 0, 0, 0);
  }

  // ---- epilogue: out[t, 0:4] = mu_mid, out[t, 4:20] = mu_leaf ----
  const float bl2v = bl2[m];
  const float b2v  = (m < 4) ? b2[m] : 0.0f;
#pragma unroll
  for (int rt = 0; rt < 2; ++rt) {
#pragma unroll
    for (int j = 0; j < 4; ++j) {
      const long t = t0 + r0 + rt * 16 + g * 4 + j;  // C layout: row=(lane>>4)*4+reg, col=lane&15
      if (t < T_DATA) {
        out[t * 20 + 4 + m] = mu4[rt][j] + bl2v;
        if (m < 4) out[t * 20 + m] = mu2[rt][j] + b2v;
      }
    }
  }
}

extern "C" void kernel_launch(void* const* d_in, const int* in_sizes, int n_in,
                              void* d_out, int out_size, void* d_ws, size_t ws_size,
                              hipStream_t stream) {
  const float* V   = (const float*)d_in[0];
  const float* W1  = (const float*)d_in[1];
  const float* b1  = (const float*)d_in[2];
  const float* W2  = (const float*)d_in[3];
  const float* b2  = (const float*)d_in[4];
  const float* Wl1 = (const float*)d_in[5];
  const float* bl1 = (const float*)d_in[6];
  const float* Wl2 = (const float*)d_in[7];
  const float* bl2 = (const float*)d_in[8];
  bf16* ws = (bf16*)d_ws;   // needs 262144 bytes
  float* out = (float*)d_out;

  pack_weights<<<64, 256, 0, stream>>>(W1, W2, Wl1, Wl2, ws);

  const int grid = (T_DATA + BT - 1) / BT;   // 782
  fused_enc<<<grid, 256, 0, stream>>>(V, b1, b2, bl1, bl2, ws, out);
}

// Round 5
// 66.893 us; speedup vs baseline: 1.4678x; 1.4088x over previous
//
#include <hip/hip_runtime.h>

// LVAE_shGLM encoder, fused bf16-MFMA implementation for gfx950.
// Round 5: BT=64 (16 rows/wave -> 64-reg accumulator) so the unified
// VGPR+AGPR footprint fits 2 waves/SIMD; full-kt 16KB staged weight tiles
// (15 barriers, not 60); LDS 66.7 KB -> 2 blocks/CU. Cross-block TLP now
// hides the per-barrier vmcnt(0) drain that a single resident block cannot.
//
//   h_mid  = relu(windows @ W1 + b1)   windows[t,k] = pad[t+k]
//   mu_mid = h_mid @ W2 + b2           -> out[:, 0:4]
//   h_leaf = relu(h_mid @ Wl1 + bl1)
//   mu_leaf= h_leaf @ Wl2 + bl2        -> out[:, 4:20]

typedef __bf16 bf16;
typedef __bf16 bf16x8 __attribute__((ext_vector_type(8)));
typedef float  f32x4  __attribute__((ext_vector_type(4)));

constexpr int T_DATA = 100000;
constexpr int T_V    = 100;
constexpr int WIN    = 199;   // 2*T_V - 1
constexpr int HID    = 256;
constexpr int BT     = 64;    // timesteps per block
constexpr int RPW    = 16;    // rows per wave (one MFMA row-tile)
constexpr int NKT    = 15;    // 7 (W1, K padded 199->224) + 8 (Wl1)

// ws layout in bf16 elements (written by pack_weights):
//   [0      .. 57343 ] PW1   7 kt-tiles x 16 ct x 512
//   [57344  ..122879 ] PWl1  8 kt-tiles x 16 ct x 512   (contiguous with PW1)
//   [122880 ..126975 ] PW2   8 kt x 512
//   [126976 ..131071 ] PWl2  8 kt x 512
constexpr int PW1_OFF  = 0;
constexpr int PWL1_OFF = 112 * 512;
constexpr int PW2_OFF  = PWL1_OFF + 128 * 512;   // 122880
constexpr int PWL2_OFF = PW2_OFF + 8 * 512;      // 126976

__global__ void pack_weights(const float* __restrict__ W1, const float* __restrict__ W2,
                             const float* __restrict__ Wl1, const float* __restrict__ Wl2,
                             bf16* __restrict__ ws) {
  const int gid  = blockIdx.x * blockDim.x + threadIdx.x;  // [0, 16384)
  const int lane = gid & 63;
  const int grp  = gid >> 6;        // [0, 256)
  const int m    = lane & 15;       // fragment col (N)
  const int g    = lane >> 4;       // k-group
  bf16x8 v;
  if (grp < 112) {                  // PW1: grp = kt*16 + nt
    const int kt = grp >> 4, nt = grp & 15, n = nt * 16 + m;
#pragma unroll
    for (int j = 0; j < 8; ++j) {
      const int k = kt * 32 + g * 8 + j;
      v[j] = (k < WIN) ? (bf16)W1[k * HID + n] : (bf16)0.0f;
    }
  } else if (grp < 240) {           // PWl1
    const int q = grp - 112;
    const int kt = q >> 4, nt = q & 15, n = nt * 16 + m;
#pragma unroll
    for (int j = 0; j < 8; ++j) {
      const int k = kt * 32 + g * 8 + j;
      v[j] = (bf16)Wl1[k * HID + n];
    }
  } else if (grp < 248) {           // PW2: only cols 0..3 real, rest zero
    const int kt = grp - 240;
#pragma unroll
    for (int j = 0; j < 8; ++j) {
      const int k = kt * 32 + g * 8 + j;
      v[j] = (m < 4) ? (bf16)W2[k * 4 + m] : (bf16)0.0f;
    }
  } else {                          // PWl2: 16 cols
    const int kt = grp - 248;
#pragma unroll
    for (int j = 0; j < 8; ++j) {
      const int k = kt * 32 + g * 8 + j;
      v[j] = (bf16)Wl2[k * 16 + m];
    }
  }
  *reinterpret_cast<bf16x8*>(ws + (size_t)gid * 8) = v;
}

// Stage one 16 KB kt-tile (8192 bf16) global -> LDS. 4 global_load_lds_dwordx4
// per wave; LDS dest is wave-uniform base (HW adds lane*16), global src per-lane.
__device__ __forceinline__ void stage_tile(const bf16* __restrict__ g, bf16* l,
                                           int w, int lane) {
#pragma unroll
  for (int i = 0; i < 4; ++i) {
    const int off = (w * 4 + i) * 512;   // 1024 B per wave-instr
    __builtin_amdgcn_global_load_lds(
        (const __attribute__((address_space(1))) void*)(g + off + lane * 8),
        (__attribute__((address_space(3))) void*)(l + off), 16, 0, 0);
  }
}

__global__ __launch_bounds__(256, 1) void fused_enc(
    const float* __restrict__ V, const float* __restrict__ b1,
    const float* __restrict__ b2, const float* __restrict__ bl1,
    const float* __restrict__ bl2, const bf16* __restrict__ ws,
    float* __restrict__ out) {
  __shared__ float Vs[BT + 224];        // 1152 B fp32 window slice
  __shared__ bf16  hbuf[BT * HID];      // 32 KB, XOR-swizzled, wave-private rows
  __shared__ bf16  bwe[2][8192];        // 32 KB double-buffered full kt-tile
  // total 66688 B -> 2 blocks/CU

  const int tid  = threadIdx.x;
  const int lane = tid & 63;
  const int w    = tid >> 6;
  const int m    = lane & 15;           // A-frag row / C col
  const int g    = lane >> 4;           // k-group / C row-group
  const long t0  = (long)blockIdx.x * BT;

  // ---- prologue: stage tile 0, fill Vs ----
  stage_tile(ws, bwe[0], w, lane);
  for (int i = tid; i < BT + 224; i += 256) {
    const long src = t0 - (T_V - 1) + i;
    Vs[i] = (src >= 0 && src < T_DATA) ? V[src] : 0.0f;
  }
  __syncthreads();   // drains vmcnt: bwe[0] + Vs resident

  const int r0   = w * RPW;             // wave's first local row
  const int ar0  = r0 + m;              // A row
  const int swz0 = (ar0 & 7) << 3;

  f32x4 acc[16];
#pragma unroll
  for (int ct = 0; ct < 16; ++ct) acc[ct] = (f32x4){0.f, 0.f, 0.f, 0.f};
  f32x4 mu2 = (f32x4){0.f, 0.f, 0.f, 0.f};

  // ---- main pipeline: 15 kt phases ----
  // kt 0..6 = GEMM1 (A from Vs), kt 7..14 = GEMM3 (+fused GEMM2, A from hbuf)
#pragma unroll
  for (int kt = 0; kt < NKT; ++kt) {
    const int cur = kt & 1;
    if (kt + 1 < NKT)                       // prefetch next kt-tile
      stage_tile(ws + (size_t)(kt + 1) * 8192, bwe[cur ^ 1], w, lane);

    bf16x8 a0;
    if (kt < 7) {                           // A from sliding window (fp32 -> bf16)
      const int kb = kt * 32 + g * 8;
#pragma unroll
      for (int j = 0; j < 8; ++j) a0[j] = (bf16)Vs[ar0 + kb + j];
    } else {                                // A from swizzled h_mid in LDS
      const int kb = (kt - 7) * 32 + g * 8;
      a0 = *reinterpret_cast<const bf16x8*>(&hbuf[ar0 * HID + (kb ^ swz0)]);
    }

    const bf16* bp = bwe[cur] + lane * 8;
#pragma unroll
    for (int ct = 0; ct < 16; ++ct) {
      const bf16x8 b = *reinterpret_cast<const bf16x8*>(bp + ct * 512);
      acc[ct] = __builtin_amdgcn_mfma_f32_16x16x32_bf16(a0, b, acc[ct], 0, 0, 0);
    }

    if (kt >= 7) {                          // fused GEMM2: mu_mid += h_mid_k @ W2_k
      const bf16x8 bw2 = *reinterpret_cast<const bf16x8*>(
          ws + PW2_OFF + (size_t)(kt - 7) * 512 + lane * 8);
      mu2 = __builtin_amdgcn_mfma_f32_16x16x32_bf16(a0, bw2, mu2, 0, 0, 0);
    }

    if (kt == 6) {
      // h_mid epilogue: bias+relu, store to own hbuf rows (swizzled), reset acc
#pragma unroll
      for (int ct = 0; ct < 16; ++ct) {
        const float bb = b1[ct * 16 + m];
#pragma unroll
        for (int j = 0; j < 4; ++j) {
          const int r = r0 + g * 4 + j;
          float h = fmaxf(acc[ct][j] + bb, 0.0f);
          const int c = ct * 16 + m;
          hbuf[r * HID + (c ^ ((r & 7) << 3))] = (bf16)h;
          acc[ct][j] = 0.0f;
        }
      }
    }
    __syncthreads();   // all waves done with bwe[cur]; next tile landed
  }

  // ---- h_leaf epilogue: bias+relu, overwrite own hbuf rows ----
#pragma unroll
  for (int ct = 0; ct < 16; ++ct) {
    const float bb = bl1[ct * 16 + m];
#pragma unroll
    for (int j = 0; j < 4; ++j) {
      const int r = r0 + g * 4 + j;
      float h = fmaxf(acc[ct][j] + bb, 0.0f);
      const int c = ct * 16 + m;
      hbuf[r * HID + (c ^ ((r & 7) << 3))] = (bf16)h;
    }
  }

  // ---- GEMM4: mu_leaf = h_leaf @ Wl2 (wave-private, no barriers) ----
  f32x4 mu4 = (f32x4){0.f, 0.f, 0.f, 0.f};
#pragma unroll
  for (int kq = 0; kq < 8; ++kq) {
    const int kb = kq * 32 + g * 8;
    const bf16x8 a0 = *reinterpret_cast<const bf16x8*>(&hbuf[ar0 * HID + (kb ^ swz0)]);
    const bf16x8 b  = *reinterpret_cast<const bf16x8*>(
        ws + PWL2_OFF + (size_t)kq * 512 + lane * 8);
    mu4 = __builtin_amdgcn_mfma_f32_16x16x32_bf16(a0, b, mu4, 0, 0, 0);
  }

  // ---- epilogue: out[t, 0:4] = mu_mid, out[t, 4:20] = mu_leaf ----
  const float bl2v = bl2[m];
  const float b2v  = (m < 4) ? b2[m] : 0.0f;
#pragma unroll
  for (int j = 0; j < 4; ++j) {
    const long t = t0 + r0 + g * 4 + j;   // C layout: row=(lane>>4)*4+reg, col=lane&15
    if (t < T_DATA) {
      out[t * 20 + 4 + m] = mu4[j] + bl2v;
      if (m < 4) out[t * 20 + m] = mu2[j] + b2v;
    }
  }
}

extern "C" void kernel_launch(void* const* d_in, const int* in_sizes, int n_in,
                              void* d_out, int out_size, void* d_ws, size_t ws_size,
                              hipStream_t stream) {
  const float* V   = (const float*)d_in[0];
  const float* W1  = (const float*)d_in[1];
  const float* b1  = (const float*)d_in[2];
  const float* W2  = (const float*)d_in[3];
  const float* b2  = (const float*)d_in[4];
  const float* Wl1 = (const float*)d_in[5];
  const float* bl1 = (const float*)d_in[6];
  const float* Wl2 = (const float*)d_in[7];
  const float* bl2 = (const float*)d_in[8];
  bf16* ws = (bf16*)d_ws;   // needs 262144 bytes
  float* out = (float*)d_out;

  pack_weights<<<64, 256, 0, stream>>>(W1, W2, Wl1, Wl2, ws);

  const int grid = (T_DATA + BT - 1) / BT;   // 1563
  fused_enc<<<grid, 256, 0, stream>>>(V, b1, b2, bl1, bl2, ws, out);
}

// Round 7
// 50.758 us; speedup vs baseline: 1.9344x; 1.3179x over previous
//
#include <hip/hip_runtime.h>

// LVAE_shGLM encoder, fused bf16-MFMA implementation for gfx950.
// Round 7: round-6 column-split design, but fused GEMM2 (mu_mid) moved out of
// the GEMM3 loop into a separate wave-uniform loop — the round-6 guarded MFMA
// (`if (w == rt) mfma(...)`) is the prime correctness suspect: MFMA is a
// whole-wave op and a compiler-divergent guard around it is unverified
// territory; every other construct here matches a previously-passing round.
//
//   h_mid  = relu(windows @ W1 + b1)   windows[t,k] = pad[t+k]
//   mu_mid = h_mid @ W2 + b2           -> out[:, 0:4]
//   h_leaf = relu(h_mid @ Wl1 + bl1)
//   mu_leaf= h_leaf @ Wl2 + bl2        -> out[:, 4:20]

typedef __bf16 bf16;
typedef __bf16 bf16x8 __attribute__((ext_vector_type(8)));
typedef float  f32x4  __attribute__((ext_vector_type(4)));

constexpr int T_DATA = 100000;
constexpr int T_V    = 100;
constexpr int WIN    = 199;   // 2*T_V - 1
constexpr int HID    = 256;
constexpr int BT     = 64;    // timesteps per block

// ws layout in bf16 elements (written by pack_weights):
//   [0      .. 57343 ] PW1   7 kt-tiles x 16 ct x 512
//   [57344  ..122879 ] PWl1  8 kt-tiles x 16 ct x 512
//   [122880 ..126975 ] PW2   8 kt x 512
//   [126976 ..131071 ] PWl2  8 kt x 512
constexpr int PW1_OFF  = 0;
constexpr int PWL1_OFF = 112 * 512;
constexpr int PW2_OFF  = PWL1_OFF + 128 * 512;   // 122880
constexpr int PWL2_OFF = PW2_OFF + 8 * 512;      // 126976

__global__ void pack_weights(const float* __restrict__ W1, const float* __restrict__ W2,
                             const float* __restrict__ Wl1, const float* __restrict__ Wl2,
                             bf16* __restrict__ ws) {
  const int gid  = blockIdx.x * blockDim.x + threadIdx.x;  // [0, 16384)
  const int lane = gid & 63;
  const int grp  = gid >> 6;        // [0, 256)
  const int m    = lane & 15;       // fragment col (N)
  const int g    = lane >> 4;       // k-group
  bf16x8 v;
  if (grp < 112) {                  // PW1: grp = kt*16 + nt
    const int kt = grp >> 4, nt = grp & 15, n = nt * 16 + m;
#pragma unroll
    for (int j = 0; j < 8; ++j) {
      const int k = kt * 32 + g * 8 + j;
      v[j] = (k < WIN) ? (bf16)W1[k * HID + n] : (bf16)0.0f;
    }
  } else if (grp < 240) {           // PWl1
    const int q = grp - 112;
    const int kt = q >> 4, nt = q & 15, n = nt * 16 + m;
#pragma unroll
    for (int j = 0; j < 8; ++j) {
      const int k = kt * 32 + g * 8 + j;
      v[j] = (bf16)Wl1[k * HID + n];
    }
  } else if (grp < 248) {           // PW2: only cols 0..3 real, rest zero
    const int kt = grp - 240;
#pragma unroll
    for (int j = 0; j < 8; ++j) {
      const int k = kt * 32 + g * 8 + j;
      v[j] = (m < 4) ? (bf16)W2[k * 4 + m] : (bf16)0.0f;
    }
  } else {                          // PWl2: 16 cols
    const int kt = grp - 248;
#pragma unroll
    for (int j = 0; j < 8; ++j) {
      const int k = kt * 32 + g * 8 + j;
      v[j] = (bf16)Wl2[k * 16 + m];
    }
  }
  *reinterpret_cast<bf16x8*>(ws + (size_t)gid * 8) = v;
}

__global__ __launch_bounds__(256, 1) void fused_enc(
    const float* __restrict__ V, const float* __restrict__ b1,
    const float* __restrict__ b2, const float* __restrict__ bl1,
    const float* __restrict__ bl2, const bf16* __restrict__ ws,
    float* __restrict__ out) {
  __shared__ float Vs[BT + 224];       // 1152 B fp32 window slice
  __shared__ bf16  awin[28 * 64 * 8];  // 28 KB: GEMM1 A-frags, [gk=kt*4+g][row][j]
  __shared__ bf16  hbuf[BT * HID];     // 32 KB, XOR-swizzled h_mid / h_leaf
  // total 62592 B -> 2 blocks/CU

  const int tid  = threadIdx.x;
  const int lane = tid & 63;
  const int w    = tid >> 6;            // wave id = column-stripe owner
  const int m    = lane & 15;           // frag row/col index
  const int g    = lane >> 4;           // k-group / C row-group
  const long t0  = (long)blockIdx.x * BT;

  // ---- 1. stage padded window slice (fp32) ----
  for (int i = tid; i < BT + 224; i += 256) {
    const long src = t0 - (T_V - 1) + i;
    Vs[i] = (src >= 0 && src < T_DATA) ? V[src] : 0.0f;
  }
  __syncthreads();

  // ---- 2. prebuild GEMM1 A-tile in bf16 fragment layout ----
  // chunk cid = gk*64 + r; holds windows[r][gk*8 .. gk*8+7] (k = kt*32+g*8+j)
#pragma unroll
  for (int i = 0; i < 7; ++i) {
    const int cid = i * 256 + tid;      // [0, 1792): 28 gk x 64 rows
    const int r   = cid & 63;
    const int k0  = (cid >> 6) * 8;     // gk*8 == kt*32 + g*8
    bf16x8 v;
#pragma unroll
    for (int j = 0; j < 8; ++j) v[j] = (bf16)Vs[r + k0 + j];
    *reinterpret_cast<bf16x8*>(&awin[cid * 8]) = v;
  }
  __syncthreads();

  const int swzm = (m & 7) << 3;        // row-XOR swizzle term for hbuf reads

  f32x4 acc[4][4];                      // [c][rt]: cols (4w+c)*16+m, rows rt*16+(g*4+j)
#pragma unroll
  for (int c = 0; c < 4; ++c)
#pragma unroll
    for (int rt = 0; rt < 4; ++rt) acc[c][rt] = (f32x4){0.f, 0.f, 0.f, 0.f};

  // ---- 3. GEMM1: h_mid(pre) = windows @ W1 (no barriers in loop) ----
#pragma unroll
  for (int kt = 0; kt < 7; ++kt) {
    bf16x8 bfr[4], afr[4];
#pragma unroll
    for (int c = 0; c < 4; ++c)
      bfr[c] = *reinterpret_cast<const bf16x8*>(
          ws + (size_t)(kt * 16 + 4 * w + c) * 512 + lane * 8);
#pragma unroll
    for (int rt = 0; rt < 4; ++rt)
      afr[rt] = *reinterpret_cast<const bf16x8*>(
          &awin[(((kt * 4 + g) * 64) + rt * 16 + m) * 8]);
#pragma unroll
    for (int c = 0; c < 4; ++c)
#pragma unroll
      for (int rt = 0; rt < 4; ++rt)
        acc[c][rt] = __builtin_amdgcn_mfma_f32_16x16x32_bf16(afr[rt], bfr[c], acc[c][rt], 0, 0, 0);
  }

  // ---- 4. h_mid epilogue: bias+relu -> hbuf column stripe (swizzled) ----
#pragma unroll
  for (int c = 0; c < 4; ++c) {
    const int ct = 4 * w + c;
    const float bb = b1[ct * 16 + m];
#pragma unroll
    for (int rt = 0; rt < 4; ++rt)
#pragma unroll
      for (int j = 0; j < 4; ++j) {
        const int r = rt * 16 + g * 4 + j;
        float h = fmaxf(acc[c][rt][j] + bb, 0.0f);
        hbuf[r * HID + ((ct * 16 + m) ^ ((r & 7) << 3))] = (bf16)h;
        acc[c][rt][j] = 0.0f;
      }
  }
  __syncthreads();

  // ---- 5. GEMM3: h_leaf(pre) = h_mid @ Wl1 (no divergent MFMA here) ----
#pragma unroll
  for (int kt = 0; kt < 8; ++kt) {
    const int kb = kt * 32 + g * 8;
    bf16x8 bfr[4], afr[4];
#pragma unroll
    for (int c = 0; c < 4; ++c)
      bfr[c] = *reinterpret_cast<const bf16x8*>(
          ws + PWL1_OFF + (size_t)(kt * 16 + 4 * w + c) * 512 + lane * 8);
#pragma unroll
    for (int rt = 0; rt < 4; ++rt)
      afr[rt] = *reinterpret_cast<const bf16x8*>(
          &hbuf[(rt * 16 + m) * HID + (kb ^ swzm)]);
#pragma unroll
    for (int c = 0; c < 4; ++c)
#pragma unroll
      for (int rt = 0; rt < 4; ++rt)
        acc[c][rt] = __builtin_amdgcn_mfma_f32_16x16x32_bf16(afr[rt], bfr[c], acc[c][rt], 0, 0, 0);
  }

  // ---- 5b. GEMM2: mu_mid for this wave's 16 rows (wave-uniform, h_mid intact) ----
  f32x4 mu2 = (f32x4){0.f, 0.f, 0.f, 0.f};
#pragma unroll
  for (int kt = 0; kt < 8; ++kt) {
    const int kb = kt * 32 + g * 8;
    const bf16x8 a = *reinterpret_cast<const bf16x8*>(
        &hbuf[(w * 16 + m) * HID + (kb ^ swzm)]);
    const bf16x8 bw2 = *reinterpret_cast<const bf16x8*>(
        ws + PW2_OFF + (size_t)kt * 512 + lane * 8);
    mu2 = __builtin_amdgcn_mfma_f32_16x16x32_bf16(a, bw2, mu2, 0, 0, 0);
  }
  __syncthreads();   // all h_mid reads complete before h_leaf overwrites

  // ---- 6. h_leaf epilogue: bias+relu -> hbuf column stripe ----
#pragma unroll
  for (int c = 0; c < 4; ++c) {
    const int ct = 4 * w + c;
    const float bb = bl1[ct * 16 + m];
#pragma unroll
    for (int rt = 0; rt < 4; ++rt)
#pragma unroll
      for (int j = 0; j < 4; ++j) {
        const int r = rt * 16 + g * 4 + j;
        float h = fmaxf(acc[c][rt][j] + bb, 0.0f);
        hbuf[r * HID + ((ct * 16 + m) ^ ((r & 7) << 3))] = (bf16)h;
      }
  }
  __syncthreads();

  // ---- 7. GEMM4: mu_leaf = h_leaf @ Wl2 (wave w handles rows 16w..16w+15) ----
  f32x4 mu4 = (f32x4){0.f, 0.f, 0.f, 0.f};
#pragma unroll
  for (int kq = 0; kq < 8; ++kq) {
    const int kb = kq * 32 + g * 8;
    const bf16x8 a = *reinterpret_cast<const bf16x8*>(
        &hbuf[(w * 16 + m) * HID + (kb ^ swzm)]);
    const bf16x8 b = *reinterpret_cast<const bf16x8*>(
        ws + PWL2_OFF + (size_t)kq * 512 + lane * 8);
    mu4 = __builtin_amdgcn_mfma_f32_16x16x32_bf16(a, b, mu4, 0, 0, 0);
  }

  // ---- 8. out: [t, 0:4] = mu_mid, [t, 4:20] = mu_leaf ----
  const float bl2v = bl2[m];
  const float b2v  = (m < 4) ? b2[m] : 0.0f;
#pragma unroll
  for (int j = 0; j < 4; ++j) {
    const long t = t0 + w * 16 + g * 4 + j;   // C layout: row=(lane>>4)*4+reg, col=lane&15
    if (t < T_DATA) {
      out[t * 20 + 4 + m] = mu4[j] + bl2v;
      if (m < 4) out[t * 20 + m] = mu2[j] + b2v;
    }
  }
}

extern "C" void kernel_launch(void* const* d_in, const int* in_sizes, int n_in,
                              void* d_out, int out_size, void* d_ws, size_t ws_size,
                              hipStream_t stream) {
  const float* V   = (const float*)d_in[0];
  const float* W1  = (const float*)d_in[1];
  const float* b1  = (const float*)d_in[2];
  const float* W2  = (const float*)d_in[3];
  const float* b2  = (const float*)d_in[4];
  const float* Wl1 = (const float*)d_in[5];
  const float* bl1 = (const float*)d_in[6];
  const float* Wl2 = (const float*)d_in[7];
  const float* bl2 = (const float*)d_in[8];
  bf16* ws = (bf16*)d_ws;   // needs 262144 bytes
  float* out = (float*)d_out;

  pack_weights<<<64, 256, 0, stream>>>(W1, W2, Wl1, Wl2, ws);

  const int grid = (T_DATA + BT - 1) / BT;   // 1563
  fused_enc<<<grid, 256, 0, stream>>>(V, b1, b2, bl1, bl2, ws, out);
}

// Round 8
// 46.740 us; speedup vs baseline: 2.1007x; 1.0860x over previous
//
#include <hip/hip_runtime.h>

// LVAE_shGLM encoder, fused bf16-MFMA implementation for gfx950.
// Round 8: occupancy push. awin (28 KB) replaced by a duplicated bf16 window
// (VsA/VsB, +1-element shift) -- A-frag start parity == m&1 is lane-constant,
// so each lane reads its GEMM1 A-frags as 4 aligned ds_read_b32 from a fixed
// base. hbuf XOR swizzle replaced by padded row stride 264 (528B = 4-bank
// rotation per row): aligned b128 reads, ~4-way (was ~8-way) epilogue writes.
// LDS 34.9 KB -> 4 blocks/CU (16 waves/CU).
//
//   h_mid  = relu(windows @ W1 + b1)   windows[t,k] = pad[t+k]
//   mu_mid = h_mid @ W2 + b2           -> out[:, 0:4]
//   h_leaf = relu(h_mid @ Wl1 + bl1)
//   mu_leaf= h_leaf @ Wl2 + bl2        -> out[:, 4:20]

typedef __bf16 bf16;
typedef __bf16 bf16x8 __attribute__((ext_vector_type(8)));
typedef float  f32x4  __attribute__((ext_vector_type(4)));
typedef unsigned int uintx4 __attribute__((ext_vector_type(4)));

constexpr int T_DATA = 100000;
constexpr int T_V    = 100;
constexpr int WIN    = 199;   // 2*T_V - 1
constexpr int HID    = 256;
constexpr int BT     = 64;    // timesteps per block
constexpr int HSTR   = 264;   // hbuf row stride (elems): 528 B -> 4-bank rotation
constexpr int VLEN   = BT + 224;  // 288

// ws layout in bf16 elements (written by pack_weights):
//   [0      .. 57343 ] PW1   7 kt-tiles x 16 ct x 512
//   [57344  ..122879 ] PWl1  8 kt-tiles x 16 ct x 512
//   [122880 ..126975 ] PW2   8 kt x 512
//   [126976 ..131071 ] PWl2  8 kt x 512
constexpr int PW1_OFF  = 0;
constexpr int PWL1_OFF = 112 * 512;
constexpr int PW2_OFF  = PWL1_OFF + 128 * 512;   // 122880
constexpr int PWL2_OFF = PW2_OFF + 8 * 512;      // 126976

__global__ void pack_weights(const float* __restrict__ W1, const float* __restrict__ W2,
                             const float* __restrict__ Wl1, const float* __restrict__ Wl2,
                             bf16* __restrict__ ws) {
  const int gid  = blockIdx.x * blockDim.x + threadIdx.x;  // [0, 16384)
  const int lane = gid & 63;
  const int grp  = gid >> 6;        // [0, 256)
  const int m    = lane & 15;       // fragment col (N)
  const int g    = lane >> 4;       // k-group
  bf16x8 v;
  if (grp < 112) {                  // PW1: grp = kt*16 + nt
    const int kt = grp >> 4, nt = grp & 15, n = nt * 16 + m;
#pragma unroll
    for (int j = 0; j < 8; ++j) {
      const int k = kt * 32 + g * 8 + j;
      v[j] = (k < WIN) ? (bf16)W1[k * HID + n] : (bf16)0.0f;
    }
  } else if (grp < 240) {           // PWl1
    const int q = grp - 112;
    const int kt = q >> 4, nt = q & 15, n = nt * 16 + m;
#pragma unroll
    for (int j = 0; j < 8; ++j) {
      const int k = kt * 32 + g * 8 + j;
      v[j] = (bf16)Wl1[k * HID + n];
    }
  } else if (grp < 248) {           // PW2: only cols 0..3 real, rest zero
    const int kt = grp - 240;
#pragma unroll
    for (int j = 0; j < 8; ++j) {
      const int k = kt * 32 + g * 8 + j;
      v[j] = (m < 4) ? (bf16)W2[k * 4 + m] : (bf16)0.0f;
    }
  } else {                          // PWl2: 16 cols
    const int kt = grp - 248;
#pragma unroll
    for (int j = 0; j < 8; ++j) {
      const int k = kt * 32 + g * 8 + j;
      v[j] = (bf16)Wl2[k * 16 + m];
    }
  }
  *reinterpret_cast<bf16x8*>(ws + (size_t)gid * 8) = v;
}

__global__ __launch_bounds__(256, 1) void fused_enc(
    const float* __restrict__ V, const float* __restrict__ b1,
    const float* __restrict__ b2, const float* __restrict__ bl1,
    const float* __restrict__ bl2, const bf16* __restrict__ ws,
    float* __restrict__ out) {
  __shared__ bf16 VsA[VLEN];        // VsA[i] = (bf16)pad[t0-99+i]
  __shared__ bf16 VsB[VLEN];        // VsB[i] = VsA[i+1]  (shifted copy)
  __shared__ bf16 hbuf[BT * HSTR];  // 33 KB, padded-stride h_mid / h_leaf
  // total 34944 B -> 4 blocks/CU

  const int tid  = threadIdx.x;
  const int lane = tid & 63;
  const int w    = tid >> 6;            // wave id = column-stripe owner
  const int m    = lane & 15;           // frag row/col index
  const int g    = lane >> 4;           // k-group / C row-group
  const long t0  = (long)blockIdx.x * BT;

  // ---- 1. stage padded window slice as duplicated bf16 ----
  for (int i = tid; i < VLEN; i += 256) {
    const long src = t0 - (T_V - 1) + i;
    const float v = (src >= 0 && src < T_DATA) ? V[src] : 0.0f;
    VsA[i] = (bf16)v;
    if (i > 0) VsB[i - 1] = (bf16)v;    // VsB[i-1] = VsA[i]
  }
  __syncthreads();

  // lane-constant A base: frag start s = rt*16+m+kb has parity (m&1);
  // odd lanes read VsB[s-1 .. s+6] == VsA[s .. s+7]; base is 4B-aligned.
  const bf16* VsP = (m & 1) ? (VsB - 1) : VsA;

  f32x4 acc[4][4];                      // [c][rt]: cols (4w+c)*16+m, rows rt*16+(g*4+j)
#pragma unroll
  for (int c = 0; c < 4; ++c)
#pragma unroll
    for (int rt = 0; rt < 4; ++rt) acc[c][rt] = (f32x4){0.f, 0.f, 0.f, 0.f};

  // ---- 2. GEMM1: h_mid(pre) = windows @ W1 (no barriers in loop) ----
#pragma unroll
  for (int kt = 0; kt < 7; ++kt) {
    const int kb = kt * 32 + g * 8;
    bf16x8 bfr[4], afr[4];
#pragma unroll
    for (int c = 0; c < 4; ++c)
      bfr[c] = *reinterpret_cast<const bf16x8*>(
          ws + (size_t)(kt * 16 + 4 * w + c) * 512 + lane * 8);
#pragma unroll
    for (int rt = 0; rt < 4; ++rt) {
      const unsigned int* p = reinterpret_cast<const unsigned int*>(VsP + (rt * 16 + m + kb));
      uintx4 u = {p[0], p[1], p[2], p[3]};          // 4 aligned ds_read_b32
      afr[rt] = __builtin_bit_cast(bf16x8, u);
    }
#pragma unroll
    for (int c = 0; c < 4; ++c)
#pragma unroll
      for (int rt = 0; rt < 4; ++rt)
        acc[c][rt] = __builtin_amdgcn_mfma_f32_16x16x32_bf16(afr[rt], bfr[c], acc[c][rt], 0, 0, 0);
  }

  // ---- 3. h_mid epilogue: bias+relu -> hbuf column stripe (padded stride) ----
#pragma unroll
  for (int c = 0; c < 4; ++c) {
    const int ct = 4 * w + c;
    const float bb = b1[ct * 16 + m];
#pragma unroll
    for (int rt = 0; rt < 4; ++rt)
#pragma unroll
      for (int j = 0; j < 4; ++j) {
        const int r = rt * 16 + g * 4 + j;
        float h = fmaxf(acc[c][rt][j] + bb, 0.0f);
        hbuf[r * HSTR + ct * 16 + m] = (bf16)h;
        acc[c][rt][j] = 0.0f;
      }
  }
  __syncthreads();

  // ---- 4. GEMM3: h_leaf(pre) = h_mid @ Wl1 ----
#pragma unroll
  for (int kt = 0; kt < 8; ++kt) {
    const int kb = kt * 32 + g * 8;
    bf16x8 bfr[4], afr[4];
#pragma unroll
    for (int c = 0; c < 4; ++c)
      bfr[c] = *reinterpret_cast<const bf16x8*>(
          ws + PWL1_OFF + (size_t)(kt * 16 + 4 * w + c) * 512 + lane * 8);
#pragma unroll
    for (int rt = 0; rt < 4; ++rt)
      afr[rt] = *reinterpret_cast<const bf16x8*>(&hbuf[(rt * 16 + m) * HSTR + kb]);
#pragma unroll
    for (int c = 0; c < 4; ++c)
#pragma unroll
      for (int rt = 0; rt < 4; ++rt)
        acc[c][rt] = __builtin_amdgcn_mfma_f32_16x16x32_bf16(afr[rt], bfr[c], acc[c][rt], 0, 0, 0);
  }

  // ---- 4b. GEMM2: mu_mid for this wave's 16 rows (wave-uniform) ----
  f32x4 mu2 = (f32x4){0.f, 0.f, 0.f, 0.f};
#pragma unroll
  for (int kt = 0; kt < 8; ++kt) {
    const int kb = kt * 32 + g * 8;
    const bf16x8 a = *reinterpret_cast<const bf16x8*>(&hbuf[(w * 16 + m) * HSTR + kb]);
    const bf16x8 bw2 = *reinterpret_cast<const bf16x8*>(
        ws + PW2_OFF + (size_t)kt * 512 + lane * 8);
    mu2 = __builtin_amdgcn_mfma_f32_16x16x32_bf16(a, bw2, mu2, 0, 0, 0);
  }
  __syncthreads();   // all h_mid reads complete before h_leaf overwrites

  // ---- 5. h_leaf epilogue: bias+relu -> hbuf column stripe ----
#pragma unroll
  for (int c = 0; c < 4; ++c) {
    const int ct = 4 * w + c;
    const float bb = bl1[ct * 16 + m];
#pragma unroll
    for (int rt = 0; rt < 4; ++rt)
#pragma unroll
      for (int j = 0; j < 4; ++j) {
        const int r = rt * 16 + g * 4 + j;
        float h = fmaxf(acc[c][rt][j] + bb, 0.0f);
        hbuf[r * HSTR + ct * 16 + m] = (bf16)h;
      }
  }
  __syncthreads();

  // ---- 6. GEMM4: mu_leaf = h_leaf @ Wl2 (wave w handles rows 16w..16w+15) ----
  f32x4 mu4 = (f32x4){0.f, 0.f, 0.f, 0.f};
#pragma unroll
  for (int kq = 0; kq < 8; ++kq) {
    const int kb = kq * 32 + g * 8;
    const bf16x8 a = *reinterpret_cast<const bf16x8*>(&hbuf[(w * 16 + m) * HSTR + kb]);
    const bf16x8 b = *reinterpret_cast<const bf16x8*>(
        ws + PWL2_OFF + (size_t)kq * 512 + lane * 8);
    mu4 = __builtin_amdgcn_mfma_f32_16x16x32_bf16(a, b, mu4, 0, 0, 0);
  }

  // ---- 7. out: [t, 0:4] = mu_mid, [t, 4:20] = mu_leaf ----
  const float bl2v = bl2[m];
  const float b2v  = (m < 4) ? b2[m] : 0.0f;
#pragma unroll
  for (int j = 0; j < 4; ++j) {
    const long t = t0 + w * 16 + g * 4 + j;   // C layout: row=(lane>>4)*4+reg, col=lane&15
    if (t < T_DATA) {
      out[t * 20 + 4 + m] = mu4[j] + bl2v;
      if (m < 4) out[t * 20 + m] = mu2[j] + b2v;
    }
  }
}

extern "C" void kernel_launch(void* const* d_in, const int* in_sizes, int n_in,
                              void* d_out, int out_size, void* d_ws, size_t ws_size,
                              hipStream_t stream) {
  const float* V   = (const float*)d_in[0];
  const float* W1  = (const float*)d_in[1];
  const float* b1  = (const float*)d_in[2];
  const float* W2  = (const float*)d_in[3];
  const float* b2  = (const float*)d_in[4];
  const float* Wl1 = (const float*)d_in[5];
  const float* bl1 = (const float*)d_in[6];
  const float* Wl2 = (const float*)d_in[7];
  const float* bl2 = (const float*)d_in[8];
  bf16* ws = (bf16*)d_ws;   // needs 262144 bytes
  float* out = (float*)d_out;

  pack_weights<<<64, 256, 0, stream>>>(W1, W2, Wl1, Wl2, ws);

  const int grid = (T_DATA + BT - 1) / BT;   // 1563
  fused_enc<<<grid, 256, 0, stream>>>(V, b1, b2, bl1, bl2, ws, out);
}

// Round 9
// 45.516 us; speedup vs baseline: 2.1572x; 1.0269x over previous
//
#include <hip/hip_runtime.h>

// LVAE_shGLM encoder, fused bf16-MFMA implementation for gfx950.
// Round 9: register-occupancy push. r8 post-mortem: residency was capped by
// the unified VGPR+AGPR footprint (~152/wave -> 2 waves/SIMD), NOT LDS.
// New shape: 512-thread blocks (8 waves), col-split 8 ways -> acc[2][4]=32
// regs; __launch_bounds__(512,4) caps alloc at 128 -> 4 waves/SIMD,
// 2 blocks/CU, 16 waves/CU. MFMA ignores EXEC (r6 lesson), so mu_mid is
// accumulated with a cndmask-SELECTED operand, never a guarded MFMA.
//
//   h_mid  = relu(windows @ W1 + b1)   windows[t,k] = pad[t+k]
//   mu_mid = h_mid @ W2 + b2           -> out[:, 0:4]
//   h_leaf = relu(h_mid @ Wl1 + bl1)
//   mu_leaf= h_leaf @ Wl2 + bl2        -> out[:, 4:20]

typedef __bf16 bf16;
typedef __bf16 bf16x8 __attribute__((ext_vector_type(8)));
typedef float  f32x4  __attribute__((ext_vector_type(4)));
typedef unsigned int uintx4 __attribute__((ext_vector_type(4)));

constexpr int T_DATA = 100000;
constexpr int T_V    = 100;
constexpr int WIN    = 199;   // 2*T_V - 1
constexpr int HID    = 256;
constexpr int BT     = 64;    // timesteps per block
constexpr int HSTR   = 264;   // hbuf row stride (elems)
constexpr int VLEN   = BT + 224;  // 288

// ws layout in bf16 elements (written by pack_weights):
//   [0      .. 57343 ] PW1   7 kt-tiles x 16 ct x 512
//   [57344  ..122879 ] PWl1  8 kt-tiles x 16 ct x 512
//   [122880 ..126975 ] PW2   8 kt x 512
//   [126976 ..131071 ] PWl2  8 kt x 512
constexpr int PW1_OFF  = 0;
constexpr int PWL1_OFF = 112 * 512;
constexpr int PW2_OFF  = PWL1_OFF + 128 * 512;   // 122880
constexpr int PWL2_OFF = PW2_OFF + 8 * 512;      // 126976

__global__ void pack_weights(const float* __restrict__ W1, const float* __restrict__ W2,
                             const float* __restrict__ Wl1, const float* __restrict__ Wl2,
                             bf16* __restrict__ ws) {
  const int gid  = blockIdx.x * blockDim.x + threadIdx.x;  // [0, 16384)
  const int lane = gid & 63;
  const int grp  = gid >> 6;        // [0, 256)
  const int m    = lane & 15;       // fragment col (N)
  const int g    = lane >> 4;       // k-group
  bf16x8 v;
  if (grp < 112) {                  // PW1: grp = kt*16 + nt
    const int kt = grp >> 4, nt = grp & 15, n = nt * 16 + m;
#pragma unroll
    for (int j = 0; j < 8; ++j) {
      const int k = kt * 32 + g * 8 + j;
      v[j] = (k < WIN) ? (bf16)W1[k * HID + n] : (bf16)0.0f;
    }
  } else if (grp < 240) {           // PWl1
    const int q = grp - 112;
    const int kt = q >> 4, nt = q & 15, n = nt * 16 + m;
#pragma unroll
    for (int j = 0; j < 8; ++j) {
      const int k = kt * 32 + g * 8 + j;
      v[j] = (bf16)Wl1[k * HID + n];
    }
  } else if (grp < 248) {           // PW2: only cols 0..3 real, rest zero
    const int kt = grp - 240;
#pragma unroll
    for (int j = 0; j < 8; ++j) {
      const int k = kt * 32 + g * 8 + j;
      v[j] = (m < 4) ? (bf16)W2[k * 4 + m] : (bf16)0.0f;
    }
  } else {                          // PWl2: 16 cols
    const int kt = grp - 248;
#pragma unroll
    for (int j = 0; j < 8; ++j) {
      const int k = kt * 32 + g * 8 + j;
      v[j] = (bf16)Wl2[k * 16 + m];
    }
  }
  *reinterpret_cast<bf16x8*>(ws + (size_t)gid * 8) = v;
}

__global__ __launch_bounds__(512, 4) void fused_enc(
    const float* __restrict__ V, const float* __restrict__ b1,
    const float* __restrict__ b2, const float* __restrict__ bl1,
    const float* __restrict__ bl2, const bf16* __restrict__ ws,
    float* __restrict__ out) {
  __shared__ bf16 VsA[VLEN];        // VsA[i] = (bf16)pad[t0-99+i]
  __shared__ bf16 VsB[VLEN];        // VsB[i] = VsA[i+1]  (shifted copy)
  __shared__ bf16 hbuf[BT * HSTR];  // 33 KB, padded-stride h_mid / h_leaf
  // total 34944 B -> 2 blocks/CU (reg-limited), 4 by LDS

  const int tid  = threadIdx.x;
  const int lane = tid & 63;
  const int w    = tid >> 6;            // wave id [0,8): owns ct {2w, 2w+1}
  const int wr   = w & 3;               // mu-row group: rows 16*wr..16*wr+15
  const int m    = lane & 15;           // frag row/col index
  const int g    = lane >> 4;           // k-group / C row-group
  const long t0  = (long)blockIdx.x * BT;

  // ---- 1. stage padded window slice as duplicated bf16 ----
  for (int i = tid; i < VLEN; i += 512) {
    const long src = t0 - (T_V - 1) + i;
    const float v = (src >= 0 && src < T_DATA) ? V[src] : 0.0f;
    VsA[i] = (bf16)v;
    if (i > 0) VsB[i - 1] = (bf16)v;    // VsB[i-1] = VsA[i]
  }
  __syncthreads();

  // lane-constant A base: frag start s = rt*16+m+kb has parity (m&1);
  // odd lanes read VsB[s-1 .. s+6] == VsA[s .. s+7]; base is 4B-aligned.
  const bf16* VsP = (m & 1) ? (VsB - 1) : VsA;

  f32x4 acc[2][4];                      // [c][rt]: col (2w+c)*16+m, rows rt*16+(g*4+j)
#pragma unroll
  for (int c = 0; c < 2; ++c)
#pragma unroll
    for (int rt = 0; rt < 4; ++rt) acc[c][rt] = (f32x4){0.f, 0.f, 0.f, 0.f};

  // ---- 2. GEMM1: h_mid(pre) = windows @ W1 ----
#pragma unroll
  for (int kt = 0; kt < 7; ++kt) {
    const int kb = kt * 32 + g * 8;
    bf16x8 bfr[2], afr[4];
#pragma unroll
    for (int c = 0; c < 2; ++c)
      bfr[c] = *reinterpret_cast<const bf16x8*>(
          ws + (size_t)(kt * 16 + 2 * w + c) * 512 + lane * 8);
#pragma unroll
    for (int rt = 0; rt < 4; ++rt) {
      const unsigned int* p = reinterpret_cast<const unsigned int*>(VsP + (rt * 16 + m + kb));
      uintx4 u = {p[0], p[1], p[2], p[3]};          // 4 aligned ds_read_b32
      afr[rt] = __builtin_bit_cast(bf16x8, u);
    }
#pragma unroll
    for (int c = 0; c < 2; ++c)
#pragma unroll
      for (int rt = 0; rt < 4; ++rt)
        acc[c][rt] = __builtin_amdgcn_mfma_f32_16x16x32_bf16(afr[rt], bfr[c], acc[c][rt], 0, 0, 0);
  }

  // ---- 3. h_mid epilogue: bias+relu -> hbuf column stripe ----
#pragma unroll
  for (int c = 0; c < 2; ++c) {
    const int ct = 2 * w + c;
    const float bb = b1[ct * 16 + m];
#pragma unroll
    for (int rt = 0; rt < 4; ++rt)
#pragma unroll
      for (int j = 0; j < 4; ++j) {
        const int r = rt * 16 + g * 4 + j;
        float h = fmaxf(acc[c][rt][j] + bb, 0.0f);
        hbuf[r * HSTR + ct * 16 + m] = (bf16)h;
        acc[c][rt][j] = 0.0f;
      }
  }
  __syncthreads();

  // ---- 4. GEMM3: h_leaf(pre) = h_mid @ Wl1, mu_mid inline (operand-select) ----
  f32x4 mu2 = (f32x4){0.f, 0.f, 0.f, 0.f};
#pragma unroll
  for (int kt = 0; kt < 8; ++kt) {
    const int kb = kt * 32 + g * 8;
    bf16x8 bfr[2], afr[4];
#pragma unroll
    for (int c = 0; c < 2; ++c)
      bfr[c] = *reinterpret_cast<const bf16x8*>(
          ws + PWL1_OFF + (size_t)(kt * 16 + 2 * w + c) * 512 + lane * 8);
#pragma unroll
    for (int rt = 0; rt < 4; ++rt)
      afr[rt] = *reinterpret_cast<const bf16x8*>(&hbuf[(rt * 16 + m) * HSTR + kb]);
#pragma unroll
    for (int c = 0; c < 2; ++c)
#pragma unroll
      for (int rt = 0; rt < 4; ++rt)
        acc[c][rt] = __builtin_amdgcn_mfma_f32_16x16x32_bf16(afr[rt], bfr[c], acc[c][rt], 0, 0, 0);
    // select this wave's mu-row fragment (cndmask on operand, MFMA unguarded)
    bf16x8 amu = afr[0];
#pragma unroll
    for (int rt = 1; rt < 4; ++rt) amu = (wr == rt) ? afr[rt] : amu;
    const bf16x8 bw2 = *reinterpret_cast<const bf16x8*>(
        ws + PW2_OFF + (size_t)kt * 512 + lane * 8);
    mu2 = __builtin_amdgcn_mfma_f32_16x16x32_bf16(amu, bw2, mu2, 0, 0, 0);
  }
  __syncthreads();   // all h_mid reads complete before h_leaf overwrites

  // ---- 5. h_leaf epilogue: bias+relu -> hbuf column stripe ----
#pragma unroll
  for (int c = 0; c < 2; ++c) {
    const int ct = 2 * w + c;
    const float bb = bl1[ct * 16 + m];
#pragma unroll
    for (int rt = 0; rt < 4; ++rt)
#pragma unroll
      for (int j = 0; j < 4; ++j) {
        const int r = rt * 16 + g * 4 + j;
        float h = fmaxf(acc[c][rt][j] + bb, 0.0f);
        hbuf[r * HSTR + ct * 16 + m] = (bf16)h;
      }
  }
  __syncthreads();

  // ---- 6. GEMM4: mu_leaf for rows 16*wr (all waves compute; half store) ----
  f32x4 mu4 = (f32x4){0.f, 0.f, 0.f, 0.f};
#pragma unroll
  for (int kq = 0; kq < 8; ++kq) {
    const int kb = kq * 32 + g * 8;
    const bf16x8 a = *reinterpret_cast<const bf16x8*>(&hbuf[(wr * 16 + m) * HSTR + kb]);
    const bf16x8 b = *reinterpret_cast<const bf16x8*>(
        ws + PWL2_OFF + (size_t)kq * 512 + lane * 8);
    mu4 = __builtin_amdgcn_mfma_f32_16x16x32_bf16(a, b, mu4, 0, 0, 0);
  }

  // ---- 7. out: waves 0-3 store mu_mid cols, waves 4-7 store mu_leaf cols ----
  const float bl2v = bl2[m];
  const float b2v  = (m < 4) ? b2[m] : 0.0f;
#pragma unroll
  for (int j = 0; j < 4; ++j) {
    const long t = t0 + wr * 16 + g * 4 + j;  // C layout: row=(lane>>4)*4+reg, col=lane&15
    if (t < T_DATA) {
      if (w >= 4) {
        out[t * 20 + 4 + m] = mu4[j] + bl2v;
      } else if (m < 4) {
        out[t * 20 + m] = mu2[j] + b2v;
      }
    }
  }
}

extern "C" void kernel_launch(void* const* d_in, const int* in_sizes, int n_in,
                              void* d_out, int out_size, void* d_ws, size_t ws_size,
                              hipStream_t stream) {
  const float* V   = (const float*)d_in[0];
  const float* W1  = (const float*)d_in[1];
  const float* b1  = (const float*)d_in[2];
  const float* W2  = (const float*)d_in[3];
  const float* b2  = (const float*)d_in[4];
  const float* Wl1 = (const float*)d_in[5];
  const float* bl1 = (const float*)d_in[6];
  const float* Wl2 = (const float*)d_in[7];
  const float* bl2 = (const float*)d_in[8];
  bf16* ws = (bf16*)d_ws;   // needs 262144 bytes
  float* out = (float*)d_out;

  pack_weights<<<64, 256, 0, stream>>>(W1, W2, Wl1, Wl2, ws);

  const int grid = (T_DATA + BT - 1) / BT;   // 1563
  fused_enc<<<grid, 512, 0, stream>>>(V, b1, b2, bl1, bl2, ws, out);
}

// Round 10
// 43.761 us; speedup vs baseline: 2.2437x; 1.0401x over previous
//
#include <hip/hip_runtime.h>

// LVAE_shGLM encoder, fused bf16-MFMA implementation for gfx950.
// Round 10: instruction-count attack. r9 post-mortem: occupancy 16->30% moved
// time only 3% -> per-wave serial work is the wall, not TLP. Switch to
// mfma_f32_32x32x16_bf16 (2x FLOP/instr, 2x FLOP/operand-byte): 136->66 MFMA,
// all A-frags single aligned ds_read_b128 (8-fold shifted window Vdup kills
// the 112 ds_read_b32), mu dup removed via pointer-selected A/B (never an
// EXEC-guarded MFMA - r6), separate hmid/hleaf buffers drop a WAR barrier.
//
//   h_mid  = relu(windows @ W1 + b1)   windows[t,k] = pad[t+k]
//   mu_mid = h_mid @ W2 + b2           -> out[:, 0:4]
//   h_leaf = relu(h_mid @ Wl1 + bl1)
//   mu_leaf= h_leaf @ Wl2 + bl2        -> out[:, 4:20]

typedef __bf16 bf16;
typedef __bf16 bf16x8 __attribute__((ext_vector_type(8)));
typedef float  f32x4  __attribute__((ext_vector_type(4)));
typedef float  f32x16 __attribute__((ext_vector_type(16)));

constexpr int T_DATA = 100000;
constexpr int T_V    = 100;
constexpr int WIN    = 199;   // 2*T_V - 1
constexpr int HID    = 256;
constexpr int BT     = 64;    // timesteps per block
constexpr int HSTR   = 264;   // h-buffer row stride (elems); 528B = 4-bank rot/row
constexpr int VLEN   = 288;   // window span: 64 rows + 207 max k + 8 frag + pad
constexpr int VSTR   = 296;   // Vdup row stride (592B, 16B-aligned)

// ws layout in bf16 elements (written by pack_weights), 1KB groups:
//   [0*512     ..) PW1_32   13 kt(K=16) x 8 nt(32 cols)  = 104 groups (k>=199 zeroed)
//   [104*512   ..) PWL1_32  16 kt x 8 nt                 = 128 groups
//   [232*512   ..) PW2      8 kt(K=32), 16x16 frag, cols 0..3 real
//   [240*512   ..) PWL2     8 kt(K=32), 16x16 frag, 16 cols
constexpr int PWL1_OFF = 104 * 512;
constexpr int PW2_OFF  = 232 * 512;
constexpr int PWL2_OFF = 240 * 512;   // total 248 KB <= ws

__global__ void pack_weights(const float* __restrict__ W1, const float* __restrict__ W2,
                             const float* __restrict__ Wl1, const float* __restrict__ Wl2,
                             bf16* __restrict__ ws) {
  const int gid  = blockIdx.x * blockDim.x + threadIdx.x;  // [0, 15872)
  const int lane = gid & 63;
  const int grp  = gid >> 6;        // [0, 248)
  bf16x8 v;
  if (grp < 104) {                  // PW1_32: 32x32x16 B frag: col=lane&31, k=(lane>>5)*8+j
    const int kt = grp >> 3, nt = grp & 7, n = nt * 32 + (lane & 31);
#pragma unroll
    for (int j = 0; j < 8; ++j) {
      const int k = kt * 16 + (lane >> 5) * 8 + j;
      v[j] = (k < WIN) ? (bf16)W1[k * HID + n] : (bf16)0.0f;
    }
  } else if (grp < 232) {           // PWL1_32
    const int q = grp - 104;
    const int kt = q >> 3, nt = q & 7, n = nt * 32 + (lane & 31);
#pragma unroll
    for (int j = 0; j < 8; ++j) {
      const int k = kt * 16 + (lane >> 5) * 8 + j;
      v[j] = (bf16)Wl1[k * HID + n];
    }
  } else if (grp < 240) {           // PW2: 16x16x32 frag: col=lane&15, k=(lane>>4)*8+j
    const int kt = grp - 232, m = lane & 15;
#pragma unroll
    for (int j = 0; j < 8; ++j) {
      const int k = kt * 32 + (lane >> 4) * 8 + j;
      v[j] = (m < 4) ? (bf16)W2[k * 4 + m] : (bf16)0.0f;
    }
  } else {                          // PWL2
    const int kt = grp - 240, m = lane & 15;
#pragma unroll
    for (int j = 0; j < 8; ++j) {
      const int k = kt * 32 + (lane >> 4) * 8 + j;
      v[j] = (bf16)Wl2[k * 16 + m];
    }
  }
  *reinterpret_cast<bf16x8*>(ws + (size_t)gid * 8) = v;
}

__global__ __launch_bounds__(512, 4) void fused_enc(
    const float* __restrict__ V, const float* __restrict__ b1,
    const float* __restrict__ b2, const float* __restrict__ bl1,
    const float* __restrict__ bl2, const bf16* __restrict__ ws,
    float* __restrict__ out) {
  __shared__ bf16 Vdup[8][VSTR];    // 4.6 KB: Vdup[p][q] = pad[t0-99+q+p]
  __shared__ bf16 hmid[BT * HSTR];  // 33 KB h_mid
  __shared__ bf16 hleaf[BT * HSTR]; // 33 KB h_leaf (separate buf -> no WAR barrier)
  // total 72320 B -> 2 blocks/CU

  const int tid  = threadIdx.x;
  const int lane = tid & 63;
  const int w    = tid >> 6;            // wave id [0,8): owns 32-col stripe w
  const int c5   = lane & 31;           // 32x32 frag col/row index
  const int hi   = lane >> 5;           // 32x32 frag k-half
  const int m    = lane & 15;           // 16x16 frag index
  const int g    = lane >> 4;           // 16x16 k-group
  const long t0  = (long)blockIdx.x * BT;

  // ---- 1. stage 8 shifted bf16 window copies ----
  for (int c = tid; c < 8 * VLEN; c += 512) {
    const int p = c / VLEN, q = c - p * VLEN;
    const long src = t0 + q + p - (T_V - 1);
    const float v = (src >= 0 && src < T_DATA) ? V[src] : 0.0f;
    Vdup[p][q] = (bf16)v;
  }
  __syncthreads();

  // A-frag element offset s = (c5 + rt*32) + kt*16 + hi*8 + j; s mod 8 = lane&7
  // (lane-constant) -> copy p = lane&7 gives a 16B-aligned single b128 read.
  const int p  = lane & 7;
  const int qb = (c5 + hi * 8) - p;     // aligned base within Vdup row p
  const bf16* vrow = &Vdup[p][0];

  f32x16 acc0 = {}, acc1 = {};          // row-tiles 0 (rows 0-31) and 1 (32-63)

  // ---- 2. GEMM1: h_mid(pre) = windows @ W1, 13 kt of K=16 ----
#pragma unroll
  for (int kt = 0; kt < 13; ++kt) {
    const bf16x8 b  = *reinterpret_cast<const bf16x8*>(
        ws + (size_t)(kt * 8 + w) * 512 + lane * 8);
    const bf16x8 a0 = *reinterpret_cast<const bf16x8*>(vrow + qb + kt * 16);
    const bf16x8 a1 = *reinterpret_cast<const bf16x8*>(vrow + qb + kt * 16 + 32);
    acc0 = __builtin_amdgcn_mfma_f32_32x32x16_bf16(a0, b, acc0, 0, 0, 0);
    acc1 = __builtin_amdgcn_mfma_f32_32x32x16_bf16(a1, b, acc1, 0, 0, 0);
  }

  // ---- 3. h_mid epilogue: bias+relu -> hmid (one bias value per lane) ----
  // C/D 32x32 layout: col = lane&31, row = (r&3) + 8*(r>>2) + 4*(lane>>5)
  const int   col = w * 32 + c5;
  const float bb1 = b1[col];
#pragma unroll
  for (int r = 0; r < 16; ++r) {
    const int row = (r & 3) + 8 * (r >> 2) + 4 * hi;
    hmid[row * HSTR + col]        = (bf16)fmaxf(acc0[r] + bb1, 0.0f);
    hmid[(row + 32) * HSTR + col] = (bf16)fmaxf(acc1[r] + bb1, 0.0f);
  }
  __syncthreads();   // B1: h_mid visible

  // ---- 4. GEMM3: h_leaf(pre) = h_mid @ Wl1, 16 kt of K=16 ----
  acc0 = (f32x16){};
  acc1 = (f32x16){};
#pragma unroll
  for (int kt = 0; kt < 16; ++kt) {
    const bf16x8 b  = *reinterpret_cast<const bf16x8*>(
        ws + PWL1_OFF + (size_t)(kt * 8 + w) * 512 + lane * 8);
    const int koff = kt * 16 + hi * 8;
    const bf16x8 a0 = *reinterpret_cast<const bf16x8*>(&hmid[c5 * HSTR + koff]);
    const bf16x8 a1 = *reinterpret_cast<const bf16x8*>(&hmid[(32 + c5) * HSTR + koff]);
    acc0 = __builtin_amdgcn_mfma_f32_32x32x16_bf16(a0, b, acc0, 0, 0, 0);
    acc1 = __builtin_amdgcn_mfma_f32_32x32x16_bf16(a1, b, acc1, 0, 0, 0);
  }

  // ---- 5. h_leaf epilogue: bias+relu -> hleaf (no barrier needed before) ----
  const float bbl = bl1[col];
#pragma unroll
  for (int r = 0; r < 16; ++r) {
    const int row = (r & 3) + 8 * (r >> 2) + 4 * hi;
    hleaf[row * HSTR + col]        = (bf16)fmaxf(acc0[r] + bbl, 0.0f);
    hleaf[(row + 32) * HSTR + col] = (bf16)fmaxf(acc1[r] + bbl, 0.0f);
  }
  __syncthreads();   // B2: h_leaf visible (hmid still intact)

  // ---- 6. mu loop: waves 0-3 -> mu_mid from hmid/PW2; waves 4-7 -> mu_leaf
  //         from hleaf/PWL2. Pointer-selected operands; MFMA itself uniform. ----
  const bf16* hb   = (w < 4) ? hmid : hleaf;
  const bf16* bwp  = ws + ((w < 4) ? PW2_OFF : PWL2_OFF);
  const int   wr   = w & 3;             // row block 16*wr .. 16*wr+15
  f32x4 mu = {0.f, 0.f, 0.f, 0.f};
#pragma unroll
  for (int kt = 0; kt < 8; ++kt) {
    const bf16x8 a = *reinterpret_cast<const bf16x8*>(
        &hb[(wr * 16 + m) * HSTR + kt * 32 + g * 8]);
    const bf16x8 b = *reinterpret_cast<const bf16x8*>(bwp + (size_t)kt * 512 + lane * 8);
    mu = __builtin_amdgcn_mfma_f32_16x16x32_bf16(a, b, mu, 0, 0, 0);
  }

  // ---- 7. out: [t,0:4]=mu_mid (waves 0-3), [t,4:20]=mu_leaf (waves 4-7) ----
  // C 16x16 layout: col = lane&15, row = (lane>>4)*4 + reg
  if (w < 4) {
    const float b2v = (m < 4) ? b2[m] : 0.0f;
#pragma unroll
    for (int j = 0; j < 4; ++j) {
      const long t = t0 + wr * 16 + g * 4 + j;
      if (t < T_DATA && m < 4) out[t * 20 + m] = mu[j] + b2v;
    }
  } else {
    const float blv = bl2[m];
#pragma unroll
    for (int j = 0; j < 4; ++j) {
      const long t = t0 + wr * 16 + g * 4 + j;
      if (t < T_DATA) out[t * 20 + 4 + m] = mu[j] + blv;
    }
  }
}

extern "C" void kernel_launch(void* const* d_in, const int* in_sizes, int n_in,
                              void* d_out, int out_size, void* d_ws, size_t ws_size,
                              hipStream_t stream) {
  const float* V   = (const float*)d_in[0];
  const float* W1  = (const float*)d_in[1];
  const float* b1  = (const float*)d_in[2];
  const float* W2  = (const float*)d_in[3];
  const float* b2  = (const float*)d_in[4];
  const float* Wl1 = (const float*)d_in[5];
  const float* bl1 = (const float*)d_in[6];
  const float* Wl2 = (const float*)d_in[7];
  const float* bl2 = (const float*)d_in[8];
  bf16* ws = (bf16*)d_ws;   // needs 253952 bytes
  float* out = (float*)d_out;

  pack_weights<<<62, 256, 0, stream>>>(W1, W2, Wl1, Wl2, ws);

  const int grid = (T_DATA + BT - 1) / BT;   // 1563
  fused_enc<<<grid, 512, 0, stream>>>(V, b1, b2, bl1, bl2, ws, out);
}

// Round 11
// 42.753 us; speedup vs baseline: 2.2966x; 1.0236x over previous
//
#include <hip/hip_runtime.h>

// LVAE_shGLM encoder, fused bf16-MFMA implementation for gfx950.
// Round 11: block-round attack. r9/r10 showed occupancy and instruction count
// are not the wall; time = (sequential block-rounds per CU) x (per-block
// phase-latency chain). BT=128 halves rounds (782 blocks -> ~2 rounds/CU) and
// cuts B L2-traffic 1.6x, keeping r10's verified 32x32 fragment machinery
// (Vdup mod-8 window, single-b128 A-frags, uniform pointer-free MFMAs).
// mu_mid fused into the GEMM3 phase; 4 barriers; single hbuf (WAR barrier).
//
//   h_mid  = relu(windows @ W1 + b1)   windows[t,k] = pad[t+k]
//   mu_mid = h_mid @ W2 + b2           -> out[:, 0:4]
//   h_leaf = relu(h_mid @ Wl1 + bl1)
//   mu_leaf= h_leaf @ Wl2 + bl2        -> out[:, 4:20]

typedef __bf16 bf16;
typedef __bf16 bf16x8 __attribute__((ext_vector_type(8)));
typedef float  f32x4  __attribute__((ext_vector_type(4)));
typedef float  f32x16 __attribute__((ext_vector_type(16)));

constexpr int T_DATA = 100000;
constexpr int T_V    = 100;
constexpr int WIN    = 199;   // 2*T_V - 1
constexpr int HID    = 256;
constexpr int BT     = 128;   // timesteps per block
constexpr int HSTR   = 264;   // h-buffer row stride (elems); 528B = 4-bank rot/row
constexpr int VLEN   = 352;   // window span: 128 rows + 207 max k + 8 frag + pad
constexpr int VSTR   = 360;   // Vdup row stride (720B, 16B-aligned)

// ws layout in bf16 elements (written by pack_weights), 1KB groups:
//   [0*512     ..) PW1_32   13 kt(K=16) x 8 nt(32 cols)  = 104 groups (k>=199 zeroed)
//   [104*512   ..) PWL1_32  16 kt x 8 nt                 = 128 groups
//   [232*512   ..) PW2      8 kt(K=32), 16x16 frag, cols 0..3 real
//   [240*512   ..) PWL2     8 kt(K=32), 16x16 frag, 16 cols
constexpr int PWL1_OFF = 104 * 512;
constexpr int PW2_OFF  = 232 * 512;
constexpr int PWL2_OFF = 240 * 512;   // total 248 KB <= ws

__global__ void pack_weights(const float* __restrict__ W1, const float* __restrict__ W2,
                             const float* __restrict__ Wl1, const float* __restrict__ Wl2,
                             bf16* __restrict__ ws) {
  const int gid  = blockIdx.x * blockDim.x + threadIdx.x;  // [0, 15872)
  const int lane = gid & 63;
  const int grp  = gid >> 6;        // [0, 248)
  bf16x8 v;
  if (grp < 104) {                  // PW1_32: 32x32x16 B frag: col=lane&31, k=(lane>>5)*8+j
    const int kt = grp >> 3, nt = grp & 7, n = nt * 32 + (lane & 31);
#pragma unroll
    for (int j = 0; j < 8; ++j) {
      const int k = kt * 16 + (lane >> 5) * 8 + j;
      v[j] = (k < WIN) ? (bf16)W1[k * HID + n] : (bf16)0.0f;
    }
  } else if (grp < 232) {           // PWL1_32
    const int q = grp - 104;
    const int kt = q >> 3, nt = q & 7, n = nt * 32 + (lane & 31);
#pragma unroll
    for (int j = 0; j < 8; ++j) {
      const int k = kt * 16 + (lane >> 5) * 8 + j;
      v[j] = (bf16)Wl1[k * HID + n];
    }
  } else if (grp < 240) {           // PW2: 16x16x32 frag: col=lane&15, k=(lane>>4)*8+j
    const int kt = grp - 232, m = lane & 15;
#pragma unroll
    for (int j = 0; j < 8; ++j) {
      const int k = kt * 32 + (lane >> 4) * 8 + j;
      v[j] = (m < 4) ? (bf16)W2[k * 4 + m] : (bf16)0.0f;
    }
  } else {                          // PWL2
    const int kt = grp - 240, m = lane & 15;
#pragma unroll
    for (int j = 0; j < 8; ++j) {
      const int k = kt * 32 + (lane >> 4) * 8 + j;
      v[j] = (bf16)Wl2[k * 16 + m];
    }
  }
  *reinterpret_cast<bf16x8*>(ws + (size_t)gid * 8) = v;
}

__global__ __launch_bounds__(512, 4) void fused_enc(
    const float* __restrict__ V, const float* __restrict__ b1,
    const float* __restrict__ b2, const float* __restrict__ bl1,
    const float* __restrict__ bl2, const bf16* __restrict__ ws,
    float* __restrict__ out) {
  __shared__ bf16 Vdup[8][VSTR];    // 5.8 KB: Vdup[p][q] = pad[t0-99+q+p]
  __shared__ bf16 hbuf[BT * HSTR];  // 67.6 KB: h_mid, then h_leaf (WAR barrier)
  // total 73344 B -> 2 blocks/CU

  const int tid  = threadIdx.x;
  const int lane = tid & 63;
  const int w    = tid >> 6;            // wave id [0,8): owns 32-col stripe w
  const int c5   = lane & 31;           // 32x32 frag col/row index
  const int hi   = lane >> 5;           // 32x32 frag k-half
  const int m    = lane & 15;           // 16x16 frag index
  const int g    = lane >> 4;           // 16x16 k-group
  const long t0  = (long)blockIdx.x * BT;

  // ---- 1. stage 8 shifted bf16 window copies ----
  for (int c = tid; c < 8 * VLEN; c += 512) {
    const int p = c / VLEN, q = c - p * VLEN;
    const long src = t0 + q + p - (T_V - 1);
    const float v = (src >= 0 && src < T_DATA) ? V[src] : 0.0f;
    Vdup[p][q] = (bf16)v;
  }
  __syncthreads();   // B0

  // A-frag element s = (c5 + rt*32) + kt*16 + hi*8 + j; s mod 8 = lane&7
  // (lane-constant) -> copy p = lane&7 gives a 16B-aligned single b128 read.
  const int p  = lane & 7;
  const int qb = (c5 + hi * 8) - p;     // aligned base within Vdup row p
  const bf16* vrow = &Vdup[p][0];

  f32x16 acc[4];                        // row-tiles rt: rows rt*32 .. rt*32+31
#pragma unroll
  for (int rt = 0; rt < 4; ++rt) acc[rt] = (f32x16){};

  // ---- 2. GEMM1: h_mid(pre) = windows @ W1, 13 kt of K=16 ----
#pragma unroll
  for (int kt = 0; kt < 13; ++kt) {
    const bf16x8 b = *reinterpret_cast<const bf16x8*>(
        ws + (size_t)(kt * 8 + w) * 512 + lane * 8);
#pragma unroll
    for (int rt = 0; rt < 4; ++rt) {
      const bf16x8 a = *reinterpret_cast<const bf16x8*>(vrow + qb + kt * 16 + rt * 32);
      acc[rt] = __builtin_amdgcn_mfma_f32_32x32x16_bf16(a, b, acc[rt], 0, 0, 0);
    }
  }

  // ---- 3. h_mid epilogue: bias+relu -> hbuf ----
  // C/D 32x32 layout: col = lane&31, row = rt*32 + (r&3) + 8*(r>>2) + 4*(lane>>5)
  const int   col = w * 32 + c5;
  const float bb1 = b1[col];
#pragma unroll
  for (int rt = 0; rt < 4; ++rt)
#pragma unroll
    for (int r = 0; r < 16; ++r) {
      const int row = rt * 32 + (r & 3) + 8 * (r >> 2) + 4 * hi;
      hbuf[row * HSTR + col] = (bf16)fmaxf(acc[rt][r] + bb1, 0.0f);
    }
  __syncthreads();   // B1: h_mid visible

  // ---- 4. GEMM3: h_leaf(pre) = h_mid @ Wl1, 16 kt of K=16 ----
#pragma unroll
  for (int rt = 0; rt < 4; ++rt) acc[rt] = (f32x16){};
#pragma unroll
  for (int kt = 0; kt < 16; ++kt) {
    const bf16x8 b = *reinterpret_cast<const bf16x8*>(
        ws + PWL1_OFF + (size_t)(kt * 8 + w) * 512 + lane * 8);
    const int koff = kt * 16 + hi * 8;
#pragma unroll
    for (int rt = 0; rt < 4; ++rt) {
      const bf16x8 a = *reinterpret_cast<const bf16x8*>(&hbuf[(rt * 32 + c5) * HSTR + koff]);
      acc[rt] = __builtin_amdgcn_mfma_f32_32x32x16_bf16(a, b, acc[rt], 0, 0, 0);
    }
  }

  // ---- 4b. mu_mid for this wave's 16 rows (reads hmid; store needs no barrier) ----
  f32x4 mu = {0.f, 0.f, 0.f, 0.f};
#pragma unroll
  for (int kt = 0; kt < 8; ++kt) {
    const bf16x8 a = *reinterpret_cast<const bf16x8*>(
        &hbuf[(w * 16 + m) * HSTR + kt * 32 + g * 8]);
    const bf16x8 b = *reinterpret_cast<const bf16x8*>(
        ws + PW2_OFF + (size_t)kt * 512 + lane * 8);
    mu = __builtin_amdgcn_mfma_f32_16x16x32_bf16(a, b, mu, 0, 0, 0);
  }
  {
    const float b2v = (m < 4) ? b2[m] : 0.0f;
#pragma unroll
    for (int j = 0; j < 4; ++j) {       // C 16x16: col=lane&15, row=(lane>>4)*4+reg
      const long t = t0 + w * 16 + g * 4 + j;
      if (t < T_DATA && m < 4) out[t * 20 + m] = mu[j] + b2v;
    }
  }
  __syncthreads();   // B2 (WAR): all h_mid reads done before h_leaf overwrite

  // ---- 5. h_leaf epilogue: bias+relu -> hbuf ----
  const float bbl = bl1[col];
#pragma unroll
  for (int rt = 0; rt < 4; ++rt)
#pragma unroll
    for (int r = 0; r < 16; ++r) {
      const int row = rt * 32 + (r & 3) + 8 * (r >> 2) + 4 * hi;
      hbuf[row * HSTR + col] = (bf16)fmaxf(acc[rt][r] + bbl, 0.0f);
    }
  __syncthreads();   // B3: h_leaf visible

  // ---- 6. mu_leaf for this wave's 16 rows ----
  mu = (f32x4){0.f, 0.f, 0.f, 0.f};
#pragma unroll
  for (int kq = 0; kq < 8; ++kq) {
    const bf16x8 a = *reinterpret_cast<const bf16x8*>(
        &hbuf[(w * 16 + m) * HSTR + kq * 32 + g * 8]);
    const bf16x8 b = *reinterpret_cast<const bf16x8*>(
        ws + PWL2_OFF + (size_t)kq * 512 + lane * 8);
    mu = __builtin_amdgcn_mfma_f32_16x16x32_bf16(a, b, mu, 0, 0, 0);
  }
  {
    const float blv = bl2[m];
#pragma unroll
    for (int j = 0; j < 4; ++j) {
      const long t = t0 + w * 16 + g * 4 + j;
      if (t < T_DATA) out[t * 20 + 4 + m] = mu[j] + blv;
    }
  }
}

extern "C" void kernel_launch(void* const* d_in, const int* in_sizes, int n_in,
                              void* d_out, int out_size, void* d_ws, size_t ws_size,
                              hipStream_t stream) {
  const float* V   = (const float*)d_in[0];
  const float* W1  = (const float*)d_in[1];
  const float* b1  = (const float*)d_in[2];
  const float* W2  = (const float*)d_in[3];
  const float* b2  = (const float*)d_in[4];
  const float* Wl1 = (const float*)d_in[5];
  const float* bl1 = (const float*)d_in[6];
  const float* Wl2 = (const float*)d_in[7];
  const float* bl2 = (const float*)d_in[8];
  bf16* ws = (bf16*)d_ws;   // needs 253952 bytes
  float* out = (float*)d_out;

  pack_weights<<<62, 256, 0, stream>>>(W1, W2, Wl1, Wl2, ws);

  const int grid = (T_DATA + BT - 1) / BT;   // 782
  fused_enc<<<grid, 512, 0, stream>>>(V, b1, b2, bl1, bl2, ws, out);
}